// Round 2
// baseline (3603.086 us; speedup 1.0000x reference)
//
#include <hip/hip_runtime.h>
#include <math.h>

#define DD 128

// ---------------- degree / norm ----------------
__global__ __launch_bounds__(256) void k_deg(const int* __restrict__ dst, float* __restrict__ deg, int E) {
    int e = blockIdx.x * 256 + threadIdx.x;
    if (e < E) unsafeAtomicAdd(&deg[dst[e]], 1.0f);
}

__global__ __launch_bounds__(256) void k_dinv(float* __restrict__ deg, int N) {
    int i = blockIdx.x * 256 + threadIdx.x;
    if (i < N) deg[i] = rsqrtf(deg[i] + 1.0f);   // +1 = self loop; deg>0 guaranteed
}

// ---------------- GEMM: H[N,128] = X[N,128] @ W[128,128] ----------------
__global__ __launch_bounds__(256) void k_gemm(const float* __restrict__ X, const float* __restrict__ W,
                                              float* __restrict__ H, int N) {
    __shared__ __align__(16) float sW[DD * DD];   // 64 KB
    __shared__ __align__(16) float sA[64 * DD];   // 32 KB
    int tid = threadIdx.x;

    const float4* W4 = (const float4*)W;
    float4* sW4 = (float4*)sW;
#pragma unroll
    for (int i = 0; i < 16; ++i) sW4[tid + 256 * i] = W4[tid + 256 * i];

    long row0 = (long)blockIdx.x * 64;
    const float4* X4 = (const float4*)X;
    float4* sA4 = (float4*)sA;
#pragma unroll
    for (int i = 0; i < 8; ++i) {
        int idx = tid + 256 * i;         // float4 index within 64x128 tile
        int r = idx >> 5;
        float4 v = make_float4(0.f, 0.f, 0.f, 0.f);
        if (row0 + r < N) v = X4[(row0 + r) * 32 + (idx & 31)];
        sA4[idx] = v;
    }
    __syncthreads();

    int c0 = (tid & 31) * 4;     // 32 col-groups x 4 cols
    int r0 = (tid >> 5) * 8;     // 8 row-groups x 8 rows
    float acc[8][4];
#pragma unroll
    for (int i = 0; i < 8; ++i)
#pragma unroll
        for (int j = 0; j < 4; ++j) acc[i][j] = 0.f;

#pragma unroll 4
    for (int k = 0; k < DD; k += 4) {
        float4 w0 = *(const float4*)&sW[(k + 0) * DD + c0];
        float4 w1 = *(const float4*)&sW[(k + 1) * DD + c0];
        float4 w2 = *(const float4*)&sW[(k + 2) * DD + c0];
        float4 w3 = *(const float4*)&sW[(k + 3) * DD + c0];
#pragma unroll
        for (int i = 0; i < 8; ++i) {
            float4 a = *(const float4*)&sA[(r0 + i) * DD + k];
            acc[i][0] = fmaf(a.x, w0.x, acc[i][0]);
            acc[i][1] = fmaf(a.x, w0.y, acc[i][1]);
            acc[i][2] = fmaf(a.x, w0.z, acc[i][2]);
            acc[i][3] = fmaf(a.x, w0.w, acc[i][3]);
            acc[i][0] = fmaf(a.y, w1.x, acc[i][0]);
            acc[i][1] = fmaf(a.y, w1.y, acc[i][1]);
            acc[i][2] = fmaf(a.y, w1.z, acc[i][2]);
            acc[i][3] = fmaf(a.y, w1.w, acc[i][3]);
            acc[i][0] = fmaf(a.z, w2.x, acc[i][0]);
            acc[i][1] = fmaf(a.z, w2.y, acc[i][1]);
            acc[i][2] = fmaf(a.z, w2.z, acc[i][2]);
            acc[i][3] = fmaf(a.z, w2.w, acc[i][3]);
            acc[i][0] = fmaf(a.w, w3.x, acc[i][0]);
            acc[i][1] = fmaf(a.w, w3.y, acc[i][1]);
            acc[i][2] = fmaf(a.w, w3.z, acc[i][2]);
            acc[i][3] = fmaf(a.w, w3.w, acc[i][3]);
        }
    }

#pragma unroll
    for (int i = 0; i < 8; ++i) {
        long r = row0 + r0 + i;
        if (r < N) *(float4*)&H[r * DD + c0] = make_float4(acc[i][0], acc[i][1], acc[i][2], acc[i][3]);
    }
}

// ---------------- out = b + dinv[i]^2 * h[i]  (self loop + bias) ----------------
__global__ __launch_bounds__(256) void k_init_out(const float* __restrict__ h, const float* __restrict__ dinv,
                                                  const float* __restrict__ b, float* __restrict__ out, int N) {
    long idx = (long)blockIdx.x * 256 + threadIdx.x;   // over N*32 float4s
    long n = idx >> 5;
    if (n >= N) return;
    int l = idx & 31;
    float dv = dinv[n];
    dv = dv * dv;
    float4 hv = ((const float4*)h)[idx];
    float4 bv = ((const float4*)b)[l];
    float4 o = make_float4(fmaf(hv.x, dv, bv.x), fmaf(hv.y, dv, bv.y),
                           fmaf(hv.z, dv, bv.z), fmaf(hv.w, dv, bv.w));
    ((float4*)out)[idx] = o;
}

// ---------------- edge scatter: out[dst] += norm * h[src] ----------------
__global__ __launch_bounds__(256) void k_scatter(const int* __restrict__ src, const int* __restrict__ dst,
                                                 const float* __restrict__ dinv, const float* __restrict__ h,
                                                 float* __restrict__ out, int E) {
    int e = blockIdx.x * 8 + (threadIdx.x >> 5);
    if (e >= E) return;
    int lane = threadIdx.x & 31;
    int s = src[e], d = dst[e];
    float nrm = dinv[s] * dinv[d];
    float4 v = ((const float4*)(h + (size_t)s * DD))[lane];
    float* o = out + (size_t)d * DD + lane * 4;
    unsafeAtomicAdd(o + 0, v.x * nrm);
    unsafeAtomicAdd(o + 1, v.y * nrm);
    unsafeAtomicAdd(o + 2, v.z * nrm);
    unsafeAtomicAdd(o + 3, v.w * nrm);
}

// ---------------- LayerNorm + residual + SiLU ----------------
__global__ __launch_bounds__(256) void k_ln_silu(const float* __restrict__ out, const float* __restrict__ xin,
                                                 const float* __restrict__ g, const float* __restrict__ be,
                                                 float* __restrict__ xout, int N) {
    int row = blockIdx.x * 4 + (threadIdx.x >> 6);
    if (row >= N) return;
    int lane = threadIdx.x & 63;
    float2 v = ((const float2*)(out + (size_t)row * DD))[lane];
    float s = v.x + v.y;
#pragma unroll
    for (int o = 32; o > 0; o >>= 1) s += __shfl_xor(s, o, 64);
    float mu = s * (1.0f / 128.0f);
    float dx = v.x - mu, dy = v.y - mu;
    float vs = dx * dx + dy * dy;
#pragma unroll
    for (int o = 32; o > 0; o >>= 1) vs += __shfl_xor(vs, o, 64);
    float rstd = rsqrtf(vs * (1.0f / 128.0f) + 1e-5f);
    float2 gv = ((const float2*)g)[lane];
    float2 bev = ((const float2*)be)[lane];
    float2 xv = ((const float2*)(xin + (size_t)row * DD))[lane];
    float a0 = fmaf(dx * rstd, gv.x, bev.x) + xv.x;
    float a1 = fmaf(dy * rstd, gv.y, bev.y) + xv.y;
    a0 = a0 / (1.0f + expf(-a0));
    a1 = a1 / (1.0f + expf(-a1));
    ((float2*)(xout + (size_t)row * DD))[lane] = make_float2(a0, a1);
}

// ---------------- global mean pool ----------------
__global__ __launch_bounds__(256) void k_counts(const int* __restrict__ batch, float* __restrict__ counts, int N) {
    int n = blockIdx.x * 256 + threadIdx.x;
    if (n < N) unsafeAtomicAdd(&counts[batch[n]], 1.0f);
}

__global__ __launch_bounds__(256) void k_pool(const float* __restrict__ x, const int* __restrict__ batch,
                                              float* __restrict__ sums, int N) {
    long idx = (long)blockIdx.x * 256 + threadIdx.x;   // over N*32 float4s
    long n = idx >> 5;
    if (n >= N) return;
    int l = idx & 31;
    int gi = batch[n];
    float4 v = ((const float4*)x)[idx];
    float* s = sums + (size_t)gi * DD + l * 4;
    unsafeAtomicAdd(s + 0, v.x);
    unsafeAtomicAdd(s + 1, v.y);
    unsafeAtomicAdd(s + 2, v.z);
    unsafeAtomicAdd(s + 3, v.w);
}

__global__ __launch_bounds__(256) void k_final(const float* __restrict__ sums, const float* __restrict__ counts,
                                               float* __restrict__ outp, int GD) {
    int i = blockIdx.x * 256 + threadIdx.x;
    if (i < GD) outp[i] = sums[i] / fmaxf(counts[i >> 7], 1.0f);
}

extern "C" void kernel_launch(void* const* d_in, const int* in_sizes, int n_in,
                              void* d_out, int out_size, void* d_ws, size_t ws_size,
                              hipStream_t stream) {
    const float* x = (const float*)d_in[0];
    const int* edge = (const int*)d_in[1];
    const int* batch = (const int*)d_in[2];
    const float* W[3] = {(const float*)d_in[3], (const float*)d_in[7], (const float*)d_in[11]};
    const float* b[3] = {(const float*)d_in[4], (const float*)d_in[8], (const float*)d_in[12]};
    const float* g[3] = {(const float*)d_in[5], (const float*)d_in[9], (const float*)d_in[13]};
    const float* be[3] = {(const float*)d_in[6], (const float*)d_in[10], (const float*)d_in[14]};

    int N = in_sizes[0] / DD;
    int E = in_sizes[1] / 2;
    int G = out_size / DD;
    const int* srcI = edge;        // edge_index[0]
    const int* dstI = edge + E;    // edge_index[1]

    float* ws = (float*)d_ws;
    size_t ND = (size_t)N * DD;
    float* bufH = ws;               // h = x @ W
    float* bufO = ws + ND;          // aggregated out
    float* bufX = ws + 2 * ND;      // x between layers
    float* dinv = ws + 3 * ND;      // deg -> dinv, in place
    float* sums = dinv + N;
    float* counts = sums + (size_t)G * DD;

    hipMemsetAsync(dinv, 0, N * sizeof(float), stream);
    k_deg<<<(E + 255) / 256, 256, 0, stream>>>(dstI, dinv, E);
    k_dinv<<<(N + 255) / 256, 256, 0, stream>>>(dinv, N);

    const float* xin = x;
    for (int l = 0; l < 3; ++l) {
        k_gemm<<<(N + 63) / 64, 256, 0, stream>>>(xin, W[l], bufH, N);
        k_init_out<<<(int)(((long)N * 32 + 255) / 256), 256, 0, stream>>>(bufH, dinv, b[l], bufO, N);
        k_scatter<<<(E + 7) / 8, 256, 0, stream>>>(srcI, dstI, dinv, bufH, bufO, E);
        k_ln_silu<<<(N + 3) / 4, 256, 0, stream>>>(bufO, xin, g[l], be[l], bufX, N);
        xin = bufX;   // layers 1,2 run LN in-place-safe on bufX
    }

    hipMemsetAsync(sums, 0, ((size_t)G * DD + G) * sizeof(float), stream);
    k_counts<<<(N + 255) / 256, 256, 0, stream>>>(batch, counts, N);
    k_pool<<<(int)(((long)N * 32 + 255) / 256), 256, 0, stream>>>(bufX, batch, sums, N);
    k_final<<<(G * DD + 255) / 256, 256, 0, stream>>>(sums, counts, (float*)d_out, G * DD);
}

// Round 5
// 875.720 us; speedup vs baseline: 4.1144x; 4.1144x over previous
//
#include <hip/hip_runtime.h>
#include <math.h>

#define DD 128

// ---------------- degree histogram (int) ----------------
__global__ __launch_bounds__(256) void k_count(const int* __restrict__ dst, int* __restrict__ cnt, int E) {
    int e = blockIdx.x * 256 + threadIdx.x;
    if (e < E) atomicAdd(&cnt[dst[e]], 1);
}

// ---------------- single-block exclusive scan: rowptr from cnt ----------------
__global__ __launch_bounds__(1024) void k_scan(const int* __restrict__ cnt, int* __restrict__ rowptr, int N) {
    __shared__ int lds[1024];
    int t = threadIdx.x;
    int chunk = (N + 1023) >> 10;
    int base = t * chunk;
    int s = 0;
    for (int i = 0; i < chunk; ++i) { int idx = base + i; if (idx < N) s += cnt[idx]; }
    lds[t] = s;
    __syncthreads();
    for (int off = 1; off < 1024; off <<= 1) {
        int v = (t >= off) ? lds[t - off] : 0;
        __syncthreads();
        lds[t] += v;
        __syncthreads();
    }
    int run = lds[t] - s;   // exclusive prefix of this thread's chunk
    for (int i = 0; i < chunk; ++i) {
        int idx = base + i;
        if (idx < N) { rowptr[idx] = run; run += cnt[idx]; }
    }
    if (t == 1023) rowptr[N] = lds[1023];
}

// ---------------- dinv = rsqrt(cnt + 1) ----------------
__global__ __launch_bounds__(256) void k_dinv(const int* __restrict__ cnt, float* __restrict__ dinv, int N) {
    int i = blockIdx.x * 256 + threadIdx.x;
    if (i < N) dinv[i] = rsqrtf((float)cnt[i] + 1.0f);
}

// ---------------- fill adjacency: adj[rowptr[d]+pos] = (src, w) ----------------
__global__ __launch_bounds__(256) void k_fill(const int* __restrict__ src, const int* __restrict__ dst,
                                              const float* __restrict__ dinv, const int* __restrict__ rowptr,
                                              int* __restrict__ cursor, int2* __restrict__ adj, int E) {
    int e = blockIdx.x * 256 + threadIdx.x;
    if (e >= E) return;
    int s = src[e], d = dst[e];
    int pos = atomicAdd(&cursor[d], 1);
    float w = dinv[s] * dinv[d];
    adj[rowptr[d] + pos] = make_int2(s, __float_as_int(w));
}

// ---------------- GEMM: H[N,128] = X[N,128] @ W[128,128] ----------------
__global__ __launch_bounds__(256) void k_gemm(const float* __restrict__ X, const float* __restrict__ W,
                                              float* __restrict__ H, int N) {
    __shared__ __align__(16) float sW[DD * DD];
    __shared__ __align__(16) float sA[64 * DD];
    int tid = threadIdx.x;

    const float4* W4 = (const float4*)W;
    float4* sW4 = (float4*)sW;
#pragma unroll
    for (int i = 0; i < 16; ++i) sW4[tid + 256 * i] = W4[tid + 256 * i];

    long row0 = (long)blockIdx.x * 64;
    const float4* X4 = (const float4*)X;
    float4* sA4 = (float4*)sA;
#pragma unroll
    for (int i = 0; i < 8; ++i) {
        int idx = tid + 256 * i;
        int r = idx >> 5;
        float4 v = make_float4(0.f, 0.f, 0.f, 0.f);
        if (row0 + r < N) v = X4[(row0 + r) * 32 + (idx & 31)];
        sA4[idx] = v;
    }
    __syncthreads();

    int c0 = (tid & 31) * 4;
    int r0 = (tid >> 5) * 8;
    float acc[8][4];
#pragma unroll
    for (int i = 0; i < 8; ++i)
#pragma unroll
        for (int j = 0; j < 4; ++j) acc[i][j] = 0.f;

#pragma unroll 4
    for (int k = 0; k < DD; k += 4) {
        float4 w0 = *(const float4*)&sW[(k + 0) * DD + c0];
        float4 w1 = *(const float4*)&sW[(k + 1) * DD + c0];
        float4 w2 = *(const float4*)&sW[(k + 2) * DD + c0];
        float4 w3 = *(const float4*)&sW[(k + 3) * DD + c0];
#pragma unroll
        for (int i = 0; i < 8; ++i) {
            float4 a = *(const float4*)&sA[(r0 + i) * DD + k];
            acc[i][0] = fmaf(a.x, w0.x, acc[i][0]);
            acc[i][1] = fmaf(a.x, w0.y, acc[i][1]);
            acc[i][2] = fmaf(a.x, w0.z, acc[i][2]);
            acc[i][3] = fmaf(a.x, w0.w, acc[i][3]);
            acc[i][0] = fmaf(a.y, w1.x, acc[i][0]);
            acc[i][1] = fmaf(a.y, w1.y, acc[i][1]);
            acc[i][2] = fmaf(a.y, w1.z, acc[i][2]);
            acc[i][3] = fmaf(a.y, w1.w, acc[i][3]);
            acc[i][0] = fmaf(a.z, w2.x, acc[i][0]);
            acc[i][1] = fmaf(a.z, w2.y, acc[i][1]);
            acc[i][2] = fmaf(a.z, w2.z, acc[i][2]);
            acc[i][3] = fmaf(a.z, w2.w, acc[i][3]);
            acc[i][0] = fmaf(a.w, w3.x, acc[i][0]);
            acc[i][1] = fmaf(a.w, w3.y, acc[i][1]);
            acc[i][2] = fmaf(a.w, w3.z, acc[i][2]);
            acc[i][3] = fmaf(a.w, w3.w, acc[i][3]);
        }
    }

#pragma unroll
    for (int i = 0; i < 8; ++i) {
        long r = row0 + r0 + i;
        if (r < N) *(float4*)&H[r * DD + c0] = make_float4(acc[i][0], acc[i][1], acc[i][2], acc[i][3]);
    }
}

// ------- fused: aggregate (self+bias+neighbors) -> LN -> residual -> SiLU -------
__global__ __launch_bounds__(256) void k_agg(const float* __restrict__ h, const float* __restrict__ xin,
                                             const int* __restrict__ rowptr, const int2* __restrict__ adj,
                                             const float* __restrict__ dinv, const float* __restrict__ b,
                                             const float* __restrict__ g, const float* __restrict__ be,
                                             float* __restrict__ xout, int N) {
    int row = blockIdx.x * 4 + (threadIdx.x >> 6);
    if (row >= N) return;
    int lane = threadIdx.x & 63;

    float dv = dinv[row];
    float dv2 = dv * dv;
    float2 hv = ((const float2*)(h + (size_t)row * DD))[lane];
    float2 bv = ((const float2*)b)[lane];
    float2 acc = make_float2(fmaf(hv.x, dv2, bv.x), fmaf(hv.y, dv2, bv.y));

    int beg = rowptr[row], end = rowptr[row + 1];
    for (int j0 = beg; j0 < end; j0 += 64) {
        int myj = j0 + lane;
        int2 a = make_int2(0, 0);
        if (myj < end) a = adj[myj];
        int cnt = min(64, end - j0);
        for (int k = 0; k < cnt; ++k) {
            int s = __shfl(a.x, k, 64);
            float w = __int_as_float(__shfl(a.y, k, 64));
            float2 hs = ((const float2*)(h + (size_t)s * DD))[lane];
            acc.x = fmaf(w, hs.x, acc.x);
            acc.y = fmaf(w, hs.y, acc.y);
        }
    }

    // LayerNorm over 128 (2 per lane x 64 lanes)
    float ssum = acc.x + acc.y;
#pragma unroll
    for (int o = 32; o > 0; o >>= 1) ssum += __shfl_xor(ssum, o, 64);
    float mu = ssum * (1.0f / 128.0f);
    float dx0 = acc.x - mu, dx1 = acc.y - mu;
    float vs = dx0 * dx0 + dx1 * dx1;
#pragma unroll
    for (int o = 32; o > 0; o >>= 1) vs += __shfl_xor(vs, o, 64);
    float rstd = rsqrtf(vs * (1.0f / 128.0f) + 1e-5f);

    float2 gv = ((const float2*)g)[lane];
    float2 bev = ((const float2*)be)[lane];
    float2 xv = ((const float2*)(xin + (size_t)row * DD))[lane];
    float a0 = fmaf(dx0 * rstd, gv.x, bev.x) + xv.x;
    float a1 = fmaf(dx1 * rstd, gv.y, bev.y) + xv.y;
    a0 = a0 / (1.0f + expf(-a0));
    a1 = a1 / (1.0f + expf(-a1));
    ((float2*)(xout + (size_t)row * DD))[lane] = make_float2(a0, a1);
}

// ---------------- global mean pool ----------------
__global__ __launch_bounds__(256) void k_counts(const int* __restrict__ batch, float* __restrict__ counts, int N) {
    int n = blockIdx.x * 256 + threadIdx.x;
    if (n < N) unsafeAtomicAdd(&counts[batch[n]], 1.0f);
}

__global__ __launch_bounds__(256) void k_pool(const float* __restrict__ x, const int* __restrict__ batch,
                                              float* __restrict__ sums, int N) {
    long idx = (long)blockIdx.x * 256 + threadIdx.x;
    long n = idx >> 5;
    if (n >= N) return;
    int l = idx & 31;
    int gi = batch[n];
    float4 v = ((const float4*)x)[idx];
    float* s = sums + (size_t)gi * DD + l * 4;
    unsafeAtomicAdd(s + 0, v.x);
    unsafeAtomicAdd(s + 1, v.y);
    unsafeAtomicAdd(s + 2, v.z);
    unsafeAtomicAdd(s + 3, v.w);
}

__global__ __launch_bounds__(256) void k_final(const float* __restrict__ sums, const float* __restrict__ counts,
                                               float* __restrict__ outp, int GD) {
    int i = blockIdx.x * 256 + threadIdx.x;
    if (i < GD) outp[i] = sums[i] / fmaxf(counts[i >> 7], 1.0f);
}

extern "C" void kernel_launch(void* const* d_in, const int* in_sizes, int n_in,
                              void* d_out, int out_size, void* d_ws, size_t ws_size,
                              hipStream_t stream) {
    const float* x = (const float*)d_in[0];
    const int* edge = (const int*)d_in[1];
    const int* batch = (const int*)d_in[2];
    const float* W[3] = {(const float*)d_in[3], (const float*)d_in[7], (const float*)d_in[11]};
    const float* b[3] = {(const float*)d_in[4], (const float*)d_in[8], (const float*)d_in[12]};
    const float* g[3] = {(const float*)d_in[5], (const float*)d_in[9], (const float*)d_in[13]};
    const float* be[3] = {(const float*)d_in[6], (const float*)d_in[10], (const float*)d_in[14]};

    int N = in_sizes[0] / DD;
    int E = in_sizes[1] / 2;
    int G = out_size / DD;
    const int* srcI = edge;        // edge_index[0]
    const int* dstI = edge + E;    // edge_index[1]

    char* ws = (char*)d_ws;
    size_t ND = (size_t)N * DD;
    float* bufH = (float*)ws;                         ws += ND * 4;
    float* bufX = (float*)ws;                         ws += ND * 4;
    float* dinv = (float*)ws;                         ws += (size_t)N * 4;
    int* cnt = (int*)ws;                              ws += (size_t)N * 4;
    int* cursor = (int*)ws;                           ws += (size_t)N * 4;
    int* rowptr = (int*)ws;                           ws += (size_t)(N + 1) * 4;
    ws = (char*)(((uintptr_t)ws + 15) & ~(uintptr_t)15);
    int2* adj = (int2*)ws;                            ws += (size_t)E * 8;
    float* sums = (float*)ws;                         ws += (size_t)G * DD * 4;
    float* counts = (float*)ws;

    // zero cnt + cursor (adjacent), and pool buffers
    hipMemsetAsync(cnt, 0, (size_t)N * 2 * 4, stream);
    hipMemsetAsync(sums, 0, ((size_t)G * DD + G) * 4, stream);

    k_count<<<(E + 255) / 256, 256, 0, stream>>>(dstI, cnt, E);
    k_scan<<<1, 1024, 0, stream>>>(cnt, rowptr, N);
    k_dinv<<<(N + 255) / 256, 256, 0, stream>>>(cnt, dinv, N);
    k_fill<<<(E + 255) / 256, 256, 0, stream>>>(srcI, dstI, dinv, rowptr, cursor, adj, E);

    const float* xin = x;
    for (int l = 0; l < 3; ++l) {
        k_gemm<<<(N + 63) / 64, 256, 0, stream>>>(xin, W[l], bufH, N);
        k_agg<<<(N + 3) / 4, 256, 0, stream>>>(bufH, xin, rowptr, adj, dinv, b[l], g[l], be[l], bufX, N);
        xin = bufX;
    }

    k_counts<<<(N + 255) / 256, 256, 0, stream>>>(batch, counts, N);
    k_pool<<<(int)(((long)N * 32 + 255) / 256), 256, 0, stream>>>(bufX, batch, sums, N);
    k_final<<<(G * DD + 255) / 256, 256, 0, stream>>>(sums, counts, (float*)d_out, G * DD);
}

// Round 6
// 506.926 us; speedup vs baseline: 7.1077x; 1.7275x over previous
//
#include <hip/hip_runtime.h>
#include <math.h>

#define DD 128

// ---------------- degree histogram (int) ----------------
__global__ __launch_bounds__(256) void k_count(const int* __restrict__ dst, int* __restrict__ cnt, int E) {
    int e = blockIdx.x * 256 + threadIdx.x;
    if (e < E) atomicAdd(&cnt[dst[e]], 1);
}

// ---------------- single-block exclusive scan: rowptr from cnt ----------------
__global__ __launch_bounds__(1024) void k_scan(const int* __restrict__ cnt, int* __restrict__ rowptr, int N) {
    __shared__ int lds[1024];
    int t = threadIdx.x;
    int chunk = (N + 1023) >> 10;
    int base = t * chunk;
    int s = 0;
    for (int i = 0; i < chunk; ++i) { int idx = base + i; if (idx < N) s += cnt[idx]; }
    lds[t] = s;
    __syncthreads();
    for (int off = 1; off < 1024; off <<= 1) {
        int v = (t >= off) ? lds[t - off] : 0;
        __syncthreads();
        lds[t] += v;
        __syncthreads();
    }
    int run = lds[t] - s;   // exclusive prefix of this thread's chunk
    for (int i = 0; i < chunk; ++i) {
        int idx = base + i;
        if (idx < N) { rowptr[idx] = run; run += cnt[idx]; }
    }
    if (t == 1023) rowptr[N] = lds[1023];
}

// ---------------- dinv = rsqrt(cnt + 1) ----------------
__global__ __launch_bounds__(256) void k_dinv(const int* __restrict__ cnt, float* __restrict__ dinv, int N) {
    int i = blockIdx.x * 256 + threadIdx.x;
    if (i < N) dinv[i] = rsqrtf((float)cnt[i] + 1.0f);
}

// ---------------- fill adjacency: adj[rowptr[d]+pos] = (src, w) ----------------
__global__ __launch_bounds__(256) void k_fill(const int* __restrict__ src, const int* __restrict__ dst,
                                              const float* __restrict__ dinv, const int* __restrict__ rowptr,
                                              int* __restrict__ cursor, int2* __restrict__ adj, int E) {
    int e = blockIdx.x * 256 + threadIdx.x;
    if (e >= E) return;
    int s = src[e], d = dst[e];
    int pos = atomicAdd(&cursor[d], 1);
    float w = dinv[s] * dinv[d];
    adj[rowptr[d] + pos] = make_int2(s, __float_as_int(w));
}

// ---------------- GEMM: H[N,128] = X[N,128] @ W[128,128] ----------------
__global__ __launch_bounds__(256) void k_gemm(const float* __restrict__ X, const float* __restrict__ W,
                                              float* __restrict__ H, int N) {
    __shared__ __align__(16) float sW[DD * DD];
    __shared__ __align__(16) float sA[64 * DD];
    int tid = threadIdx.x;

    const float4* W4 = (const float4*)W;
    float4* sW4 = (float4*)sW;
#pragma unroll
    for (int i = 0; i < 16; ++i) sW4[tid + 256 * i] = W4[tid + 256 * i];

    long row0 = (long)blockIdx.x * 64;
    const float4* X4 = (const float4*)X;
    float4* sA4 = (float4*)sA;
#pragma unroll
    for (int i = 0; i < 8; ++i) {
        int idx = tid + 256 * i;
        int r = idx >> 5;
        float4 v = make_float4(0.f, 0.f, 0.f, 0.f);
        if (row0 + r < N) v = X4[(row0 + r) * 32 + (idx & 31)];
        sA4[idx] = v;
    }
    __syncthreads();

    int c0 = (tid & 31) * 4;
    int r0 = (tid >> 5) * 8;
    float acc[8][4];
#pragma unroll
    for (int i = 0; i < 8; ++i)
#pragma unroll
        for (int j = 0; j < 4; ++j) acc[i][j] = 0.f;

#pragma unroll 4
    for (int k = 0; k < DD; k += 4) {
        float4 w0 = *(const float4*)&sW[(k + 0) * DD + c0];
        float4 w1 = *(const float4*)&sW[(k + 1) * DD + c0];
        float4 w2 = *(const float4*)&sW[(k + 2) * DD + c0];
        float4 w3 = *(const float4*)&sW[(k + 3) * DD + c0];
#pragma unroll
        for (int i = 0; i < 8; ++i) {
            float4 a = *(const float4*)&sA[(r0 + i) * DD + k];
            acc[i][0] = fmaf(a.x, w0.x, acc[i][0]);
            acc[i][1] = fmaf(a.x, w0.y, acc[i][1]);
            acc[i][2] = fmaf(a.x, w0.z, acc[i][2]);
            acc[i][3] = fmaf(a.x, w0.w, acc[i][3]);
            acc[i][0] = fmaf(a.y, w1.x, acc[i][0]);
            acc[i][1] = fmaf(a.y, w1.y, acc[i][1]);
            acc[i][2] = fmaf(a.y, w1.z, acc[i][2]);
            acc[i][3] = fmaf(a.y, w1.w, acc[i][3]);
            acc[i][0] = fmaf(a.z, w2.x, acc[i][0]);
            acc[i][1] = fmaf(a.z, w2.y, acc[i][1]);
            acc[i][2] = fmaf(a.z, w2.z, acc[i][2]);
            acc[i][3] = fmaf(a.z, w2.w, acc[i][3]);
            acc[i][0] = fmaf(a.w, w3.x, acc[i][0]);
            acc[i][1] = fmaf(a.w, w3.y, acc[i][1]);
            acc[i][2] = fmaf(a.w, w3.z, acc[i][2]);
            acc[i][3] = fmaf(a.w, w3.w, acc[i][3]);
        }
    }

#pragma unroll
    for (int i = 0; i < 8; ++i) {
        long r = row0 + r0 + i;
        if (r < N) *(float4*)&H[r * DD + c0] = make_float4(acc[i][0], acc[i][1], acc[i][2], acc[i][3]);
    }
}

// ------- fused: aggregate (self+bias+neighbors) -> LN -> residual -> SiLU -------
__global__ __launch_bounds__(256) void k_agg(const float* __restrict__ h, const float* __restrict__ xin,
                                             const int* __restrict__ rowptr, const int2* __restrict__ adj,
                                             const float* __restrict__ dinv, const float* __restrict__ b,
                                             const float* __restrict__ g, const float* __restrict__ be,
                                             float* __restrict__ xout, int N) {
    int row = blockIdx.x * 4 + (threadIdx.x >> 6);
    if (row >= N) return;
    int lane = threadIdx.x & 63;

    float dv = dinv[row];
    float dv2 = dv * dv;
    float2 hv = ((const float2*)(h + (size_t)row * DD))[lane];
    float2 bv = ((const float2*)b)[lane];
    float2 acc = make_float2(fmaf(hv.x, dv2, bv.x), fmaf(hv.y, dv2, bv.y));

    int beg = rowptr[row], end = rowptr[row + 1];
    for (int j0 = beg; j0 < end; j0 += 64) {
        int myj = j0 + lane;
        int2 a = make_int2(0, 0);
        if (myj < end) a = adj[myj];
        int cnt = min(64, end - j0);
        for (int k = 0; k < cnt; ++k) {
            int s = __shfl(a.x, k, 64);
            float w = __int_as_float(__shfl(a.y, k, 64));
            float2 hs = ((const float2*)(h + (size_t)s * DD))[lane];
            acc.x = fmaf(w, hs.x, acc.x);
            acc.y = fmaf(w, hs.y, acc.y);
        }
    }

    // LayerNorm over 128 (2 per lane x 64 lanes)
    float ssum = acc.x + acc.y;
#pragma unroll
    for (int o = 32; o > 0; o >>= 1) ssum += __shfl_xor(ssum, o, 64);
    float mu = ssum * (1.0f / 128.0f);
    float dx0 = acc.x - mu, dx1 = acc.y - mu;
    float vs = dx0 * dx0 + dx1 * dx1;
#pragma unroll
    for (int o = 32; o > 0; o >>= 1) vs += __shfl_xor(vs, o, 64);
    float rstd = rsqrtf(vs * (1.0f / 128.0f) + 1e-5f);

    float2 gv = ((const float2*)g)[lane];
    float2 bev = ((const float2*)be)[lane];
    float2 xv = ((const float2*)(xin + (size_t)row * DD))[lane];
    float a0 = fmaf(dx0 * rstd, gv.x, bev.x) + xv.x;
    float a1 = fmaf(dx1 * rstd, gv.y, bev.y) + xv.y;
    a0 = a0 / (1.0f + expf(-a0));
    a1 = a1 / (1.0f + expf(-a1));
    ((float2*)(xout + (size_t)row * DD))[lane] = make_float2(a0, a1);
}

// ------- pool: one block per graph; batch is sorted so graph = contiguous range -------
__global__ __launch_bounds__(256) void k_pool2(const float* __restrict__ x, const int* __restrict__ batch,
                                               float* __restrict__ out, int N) {
    int gi = blockIdx.x;
    // lower_bound(batch, gi) and lower_bound(batch, gi+1)
    int lo = 0, hi = N;
    while (lo < hi) { int m = (lo + hi) >> 1; if (batch[m] < gi) lo = m + 1; else hi = m; }
    int beg = lo;
    lo = beg; hi = N;
    while (lo < hi) { int m = (lo + hi) >> 1; if (batch[m] < gi + 1) lo = m + 1; else hi = m; }
    int end = lo;

    int tid = threadIdx.x;
    int wave = tid >> 6, lane = tid & 63;
    float2 acc = make_float2(0.f, 0.f);
    for (int r = beg + wave; r < end; r += 4) {
        float2 v = ((const float2*)(x + (size_t)r * DD))[lane];
        acc.x += v.x;
        acc.y += v.y;
    }
    __shared__ float part[4][DD];
    ((float2*)part[wave])[lane] = acc;
    __syncthreads();
    if (wave == 0) {
        float sx = 0.f, sy = 0.f;
#pragma unroll
        for (int w = 0; w < 4; ++w) {
            float2 v = ((const float2*)part[w])[lane];
            sx += v.x;
            sy += v.y;
        }
        float inv = 1.0f / fmaxf((float)(end - beg), 1.0f);
        ((float2*)(out + (size_t)gi * DD))[lane] = make_float2(sx * inv, sy * inv);
    }
}

extern "C" void kernel_launch(void* const* d_in, const int* in_sizes, int n_in,
                              void* d_out, int out_size, void* d_ws, size_t ws_size,
                              hipStream_t stream) {
    const float* x = (const float*)d_in[0];
    const int* edge = (const int*)d_in[1];
    const int* batch = (const int*)d_in[2];
    const float* W[3] = {(const float*)d_in[3], (const float*)d_in[7], (const float*)d_in[11]};
    const float* b[3] = {(const float*)d_in[4], (const float*)d_in[8], (const float*)d_in[12]};
    const float* g[3] = {(const float*)d_in[5], (const float*)d_in[9], (const float*)d_in[13]};
    const float* be[3] = {(const float*)d_in[6], (const float*)d_in[10], (const float*)d_in[14]};

    int N = in_sizes[0] / DD;
    int E = in_sizes[1] / 2;
    int G = out_size / DD;
    const int* srcI = edge;        // edge_index[0]
    const int* dstI = edge + E;    // edge_index[1]

    char* ws = (char*)d_ws;
    size_t ND = (size_t)N * DD;
    float* bufH = (float*)ws;                         ws += ND * 4;
    float* bufX = (float*)ws;                         ws += ND * 4;
    float* dinv = (float*)ws;                         ws += (size_t)N * 4;
    int* cnt = (int*)ws;                              ws += (size_t)N * 4;
    int* cursor = (int*)ws;                           ws += (size_t)N * 4;
    int* rowptr = (int*)ws;                           ws += (size_t)(N + 1) * 4;
    ws = (char*)(((uintptr_t)ws + 15) & ~(uintptr_t)15);
    int2* adj = (int2*)ws;

    // zero cnt + cursor (adjacent)
    hipMemsetAsync(cnt, 0, (size_t)N * 2 * 4, stream);

    k_count<<<(E + 255) / 256, 256, 0, stream>>>(dstI, cnt, E);
    k_scan<<<1, 1024, 0, stream>>>(cnt, rowptr, N);
    k_dinv<<<(N + 255) / 256, 256, 0, stream>>>(cnt, dinv, N);
    k_fill<<<(E + 255) / 256, 256, 0, stream>>>(srcI, dstI, dinv, rowptr, cursor, adj, E);

    const float* xin = x;
    for (int l = 0; l < 3; ++l) {
        k_gemm<<<(N + 63) / 64, 256, 0, stream>>>(xin, W[l], bufH, N);
        k_agg<<<(N + 3) / 4, 256, 0, stream>>>(bufH, xin, rowptr, adj, dinv, b[l], g[l], be[l], bufX, N);
        xin = bufX;
    }

    k_pool2<<<G, 256, 0, stream>>>(bufX, batch, (float*)d_out, N);
}

// Round 8
// 422.490 us; speedup vs baseline: 8.5282x; 1.1999x over previous
//
#include <hip/hip_runtime.h>
#include <math.h>

#define DD 128

// ---------------- degree histogram (int) ----------------
__global__ __launch_bounds__(256) void k_count(const int* __restrict__ dst, int* __restrict__ cnt, int E) {
    int e = blockIdx.x * 256 + threadIdx.x;
    if (e < E) atomicAdd(&cnt[dst[e]], 1);
}

// ---------------- hierarchical scan, phase 1: per-block sums ----------------
__global__ __launch_bounds__(256) void k_scan1(const int* __restrict__ cnt, int* __restrict__ part, int N) {
    __shared__ int lds[256];
    int t = threadIdx.x;
    int i = blockIdx.x * 256 + t;
    lds[t] = (i < N) ? cnt[i] : 0;
    __syncthreads();
#pragma unroll
    for (int off = 128; off > 0; off >>= 1) {
        if (t < off) lds[t] += lds[t + off];
        __syncthreads();
    }
    if (t == 0) part[blockIdx.x] = lds[0];
}

// ---------------- phase 2: exclusive scan of partials (single small block) ----------------
__global__ __launch_bounds__(1024) void k_scan2(int* __restrict__ part, int* __restrict__ rowptr,
                                                int nblk, int N) {
    __shared__ int lds[1024];
    int t = threadIdx.x;
    int v = (t < nblk) ? part[t] : 0;
    lds[t] = v;
    __syncthreads();
    for (int off = 1; off < 1024; off <<= 1) {
        int u = (t >= off) ? lds[t - off] : 0;
        __syncthreads();
        lds[t] += u;
        __syncthreads();
    }
    if (t < nblk) part[t] = lds[t] - v;       // exclusive
    if (t == 1023) rowptr[N] = lds[1023];     // total = E
}

// ---------------- phase 3: block-local exclusive scan + offset ----------------
__global__ __launch_bounds__(256) void k_scan3(const int* __restrict__ cnt, const int* __restrict__ part,
                                               int* __restrict__ rowptr, int N) {
    __shared__ int lds[256];
    int t = threadIdx.x;
    int i = blockIdx.x * 256 + t;
    int v = (i < N) ? cnt[i] : 0;
    lds[t] = v;
    __syncthreads();
    for (int off = 1; off < 256; off <<= 1) {
        int u = (t >= off) ? lds[t - off] : 0;
        __syncthreads();
        lds[t] += u;
        __syncthreads();
    }
    if (i < N) rowptr[i] = part[blockIdx.x] + lds[t] - v;
}

// ---------------- dinv = rsqrt(cnt + 1) ----------------
__global__ __launch_bounds__(256) void k_dinv(const int* __restrict__ cnt, float* __restrict__ dinv, int N) {
    int i = blockIdx.x * 256 + threadIdx.x;
    if (i < N) dinv[i] = rsqrtf((float)cnt[i] + 1.0f);
}

// ---------------- fill adjacency: adj[rowptr[d]+pos] = (src, w) ----------------
__global__ __launch_bounds__(256) void k_fill(const int* __restrict__ src, const int* __restrict__ dst,
                                              const float* __restrict__ dinv, const int* __restrict__ rowptr,
                                              int* __restrict__ cursor, int2* __restrict__ adj, int E) {
    int e = blockIdx.x * 256 + threadIdx.x;
    if (e >= E) return;
    int s = src[e], d = dst[e];
    int pos = atomicAdd(&cursor[d], 1);
    float w = dinv[s] * dinv[d];
    adj[rowptr[d] + pos] = make_int2(s, __float_as_int(w));
}

// ---------------- GEMM: H[N,128] = X[N,128] @ W[128,128] ----------------
__global__ __launch_bounds__(256) void k_gemm(const float* __restrict__ X, const float* __restrict__ W,
                                              float* __restrict__ H, int N) {
    __shared__ __align__(16) float sW[DD * DD];
    __shared__ __align__(16) float sA[64 * DD];
    int tid = threadIdx.x;

    const float4* W4 = (const float4*)W;
    float4* sW4 = (float4*)sW;
#pragma unroll
    for (int i = 0; i < 16; ++i) sW4[tid + 256 * i] = W4[tid + 256 * i];

    long row0 = (long)blockIdx.x * 64;
    const float4* X4 = (const float4*)X;
    float4* sA4 = (float4*)sA;
#pragma unroll
    for (int i = 0; i < 8; ++i) {
        int idx = tid + 256 * i;
        int r = idx >> 5;
        float4 v = make_float4(0.f, 0.f, 0.f, 0.f);
        if (row0 + r < N) v = X4[(row0 + r) * 32 + (idx & 31)];
        sA4[idx] = v;
    }
    __syncthreads();

    int c0 = (tid & 31) * 4;
    int r0 = (tid >> 5) * 8;
    float acc[8][4];
#pragma unroll
    for (int i = 0; i < 8; ++i)
#pragma unroll
        for (int j = 0; j < 4; ++j) acc[i][j] = 0.f;

#pragma unroll 4
    for (int k = 0; k < DD; k += 4) {
        float4 w0 = *(const float4*)&sW[(k + 0) * DD + c0];
        float4 w1 = *(const float4*)&sW[(k + 1) * DD + c0];
        float4 w2 = *(const float4*)&sW[(k + 2) * DD + c0];
        float4 w3 = *(const float4*)&sW[(k + 3) * DD + c0];
#pragma unroll
        for (int i = 0; i < 8; ++i) {
            float4 a = *(const float4*)&sA[(r0 + i) * DD + k];
            acc[i][0] = fmaf(a.x, w0.x, acc[i][0]);
            acc[i][1] = fmaf(a.x, w0.y, acc[i][1]);
            acc[i][2] = fmaf(a.x, w0.z, acc[i][2]);
            acc[i][3] = fmaf(a.x, w0.w, acc[i][3]);
            acc[i][0] = fmaf(a.y, w1.x, acc[i][0]);
            acc[i][1] = fmaf(a.y, w1.y, acc[i][1]);
            acc[i][2] = fmaf(a.y, w1.z, acc[i][2]);
            acc[i][3] = fmaf(a.y, w1.w, acc[i][3]);
            acc[i][0] = fmaf(a.z, w2.x, acc[i][0]);
            acc[i][1] = fmaf(a.z, w2.y, acc[i][1]);
            acc[i][2] = fmaf(a.z, w2.z, acc[i][2]);
            acc[i][3] = fmaf(a.z, w2.w, acc[i][3]);
            acc[i][0] = fmaf(a.w, w3.x, acc[i][0]);
            acc[i][1] = fmaf(a.w, w3.y, acc[i][1]);
            acc[i][2] = fmaf(a.w, w3.z, acc[i][2]);
            acc[i][3] = fmaf(a.w, w3.w, acc[i][3]);
        }
    }

#pragma unroll
    for (int i = 0; i < 8; ++i) {
        long r = row0 + r0 + i;
        if (r < N) *(float4*)&H[r * DD + c0] = make_float4(acc[i][0], acc[i][1], acc[i][2], acc[i][3]);
    }
}

// ------- fused: aggregate (self+bias+neighbors) -> LN -> residual -> SiLU -------
__global__ __launch_bounds__(256) void k_agg(const float* __restrict__ h, const float* __restrict__ xin,
                                             const int* __restrict__ rowptr, const int2* __restrict__ adj,
                                             const float* __restrict__ dinv, const float* __restrict__ b,
                                             const float* __restrict__ g, const float* __restrict__ be,
                                             float* __restrict__ xout, int N) {
    int row = blockIdx.x * 4 + (threadIdx.x >> 6);
    if (row >= N) return;
    int lane = threadIdx.x & 63;

    float dv = dinv[row];
    float dv2 = dv * dv;
    float2 hv = ((const float2*)(h + (size_t)row * DD))[lane];
    float2 bv = ((const float2*)b)[lane];
    float2 acc = make_float2(fmaf(hv.x, dv2, bv.x), fmaf(hv.y, dv2, bv.y));

    int beg = rowptr[row], end = rowptr[row + 1];
    for (int j0 = beg; j0 < end; j0 += 64) {
        int myj = j0 + lane;
        int2 a = make_int2(0, 0);
        if (myj < end) a = adj[myj];
        int cnt = min(64, end - j0);
        for (int k = 0; k < cnt; ++k) {
            int s = __shfl(a.x, k, 64);
            float w = __int_as_float(__shfl(a.y, k, 64));
            float2 hs = ((const float2*)(h + (size_t)s * DD))[lane];
            acc.x = fmaf(w, hs.x, acc.x);
            acc.y = fmaf(w, hs.y, acc.y);
        }
    }

    // LayerNorm over 128 (2 per lane x 64 lanes)
    float ssum = acc.x + acc.y;
#pragma unroll
    for (int o = 32; o > 0; o >>= 1) ssum += __shfl_xor(ssum, o, 64);
    float mu = ssum * (1.0f / 128.0f);
    float dx0 = acc.x - mu, dx1 = acc.y - mu;
    float vs = dx0 * dx0 + dx1 * dx1;
#pragma unroll
    for (int o = 32; o > 0; o >>= 1) vs += __shfl_xor(vs, o, 64);
    float rstd = rsqrtf(vs * (1.0f / 128.0f) + 1e-5f);

    float2 gv = ((const float2*)g)[lane];
    float2 bev = ((const float2*)be)[lane];
    float2 xv = ((const float2*)(xin + (size_t)row * DD))[lane];
    float a0 = fmaf(dx0 * rstd, gv.x, bev.x) + xv.x;
    float a1 = fmaf(dx1 * rstd, gv.y, bev.y) + xv.y;
    a0 = a0 / (1.0f + expf(-a0));
    a1 = a1 / (1.0f + expf(-a1));
    ((float2*)(xout + (size_t)row * DD))[lane] = make_float2(a0, a1);
}

// ------- pool: one block per graph; batch is sorted so graph = contiguous range -------
__global__ __launch_bounds__(256) void k_pool2(const float* __restrict__ x, const int* __restrict__ batch,
                                               float* __restrict__ out, int N) {
    int gi = blockIdx.x;
    int lo = 0, hi = N;
    while (lo < hi) { int m = (lo + hi) >> 1; if (batch[m] < gi) lo = m + 1; else hi = m; }
    int beg = lo;
    lo = beg; hi = N;
    while (lo < hi) { int m = (lo + hi) >> 1; if (batch[m] < gi + 1) lo = m + 1; else hi = m; }
    int end = lo;

    int tid = threadIdx.x;
    int wave = tid >> 6, lane = tid & 63;
    float2 acc = make_float2(0.f, 0.f);
    for (int r = beg + wave; r < end; r += 4) {
        float2 v = ((const float2*)(x + (size_t)r * DD))[lane];
        acc.x += v.x;
        acc.y += v.y;
    }
    __shared__ float part[4][DD];
    ((float2*)part[wave])[lane] = acc;
    __syncthreads();
    if (wave == 0) {
        float sx = 0.f, sy = 0.f;
#pragma unroll
        for (int w = 0; w < 4; ++w) {
            float2 v = ((const float2*)part[w])[lane];
            sx += v.x;
            sy += v.y;
        }
        float inv = 1.0f / fmaxf((float)(end - beg), 1.0f);
        ((float2*)(out + (size_t)gi * DD))[lane] = make_float2(sx * inv, sy * inv);
    }
}

extern "C" void kernel_launch(void* const* d_in, const int* in_sizes, int n_in,
                              void* d_out, int out_size, void* d_ws, size_t ws_size,
                              hipStream_t stream) {
    const float* x = (const float*)d_in[0];
    const int* edge = (const int*)d_in[1];
    const int* batch = (const int*)d_in[2];
    const float* W[3] = {(const float*)d_in[3], (const float*)d_in[7], (const float*)d_in[11]};
    const float* b[3] = {(const float*)d_in[4], (const float*)d_in[8], (const float*)d_in[12]};
    const float* g[3] = {(const float*)d_in[5], (const float*)d_in[9], (const float*)d_in[13]};
    const float* be[3] = {(const float*)d_in[6], (const float*)d_in[10], (const float*)d_in[14]};

    int N = in_sizes[0] / DD;
    int E = in_sizes[1] / 2;
    int G = out_size / DD;
    const int* srcI = edge;        // edge_index[0]
    const int* dstI = edge + E;    // edge_index[1]

    int nblk = (N + 255) / 256;

    char* ws = (char*)d_ws;
    size_t ND = (size_t)N * DD;
    float* bufH = (float*)ws;                         ws += ND * 4;
    float* bufX = (float*)ws;                         ws += ND * 4;
    float* dinv = (float*)ws;                         ws += (size_t)N * 4;
    int* cnt = (int*)ws;                              ws += (size_t)N * 4;
    int* cursor = (int*)ws;                           ws += (size_t)N * 4;
    int* rowptr = (int*)ws;                           ws += (size_t)(N + 1) * 4;
    int* part = (int*)ws;                             ws += (size_t)nblk * 4;
    ws = (char*)(((uintptr_t)ws + 15) & ~(uintptr_t)15);
    int2* adj = (int2*)ws;

    // zero cnt + cursor (adjacent)
    hipMemsetAsync(cnt, 0, (size_t)N * 2 * 4, stream);

    k_count<<<(E + 255) / 256, 256, 0, stream>>>(dstI, cnt, E);
    k_scan1<<<nblk, 256, 0, stream>>>(cnt, part, N);
    k_scan2<<<1, 1024, 0, stream>>>(part, rowptr, nblk, N);
    k_scan3<<<nblk, 256, 0, stream>>>(cnt, part, rowptr, N);
    k_dinv<<<(N + 255) / 256, 256, 0, stream>>>(cnt, dinv, N);
    k_fill<<<(E + 255) / 256, 256, 0, stream>>>(srcI, dstI, dinv, rowptr, cursor, adj, E);

    const float* xin = x;
    for (int l = 0; l < 3; ++l) {
        k_gemm<<<(N + 63) / 64, 256, 0, stream>>>(xin, W[l], bufH, N);
        k_agg<<<(N + 3) / 4, 256, 0, stream>>>(bufH, xin, rowptr, adj, dinv, b[l], g[l], be[l], bufX, N);
        xin = bufX;
    }

    k_pool2<<<G, 256, 0, stream>>>(bufX, batch, (float*)d_out, N);
}

// Round 9
// 300.656 us; speedup vs baseline: 11.9841x; 1.4052x over previous
//
#include <hip/hip_runtime.h>
#include <math.h>

#define DD 128

typedef __attribute__((ext_vector_type(8))) short short8;
typedef __attribute__((ext_vector_type(4))) float f32x4;

__device__ __forceinline__ unsigned short f2b(float f) {
    unsigned int x = __float_as_uint(f);
    return (unsigned short)((x + 0x7FFFu + ((x >> 16) & 1u)) >> 16);   // RNE bf16
}
__device__ __forceinline__ float b2f(unsigned short u) {
    return __uint_as_float(((unsigned int)u) << 16);
}

// ---------------- degree histogram (int) ----------------
__global__ __launch_bounds__(256) void k_count(const int* __restrict__ dst, int* __restrict__ cnt, int E) {
    int e = blockIdx.x * 256 + threadIdx.x;
    if (e < E) atomicAdd(&cnt[dst[e]], 1);
}

// ---------------- hierarchical scan ----------------
__global__ __launch_bounds__(256) void k_scan1(const int* __restrict__ cnt, int* __restrict__ part, int N) {
    __shared__ int lds[256];
    int t = threadIdx.x;
    int i = blockIdx.x * 256 + t;
    lds[t] = (i < N) ? cnt[i] : 0;
    __syncthreads();
#pragma unroll
    for (int off = 128; off > 0; off >>= 1) {
        if (t < off) lds[t] += lds[t + off];
        __syncthreads();
    }
    if (t == 0) part[blockIdx.x] = lds[0];
}

__global__ __launch_bounds__(1024) void k_scan2(int* __restrict__ part, int* __restrict__ rowptr,
                                                int nblk, int N) {
    __shared__ int lds[1024];
    int t = threadIdx.x;
    int v = (t < nblk) ? part[t] : 0;
    lds[t] = v;
    __syncthreads();
    for (int off = 1; off < 1024; off <<= 1) {
        int u = (t >= off) ? lds[t - off] : 0;
        __syncthreads();
        lds[t] += u;
        __syncthreads();
    }
    if (t < nblk) part[t] = lds[t] - v;
    if (t == 1023) rowptr[N] = lds[1023];
}

__global__ __launch_bounds__(256) void k_scan3(const int* __restrict__ cnt, const int* __restrict__ part,
                                               int* __restrict__ rowptr, int N) {
    __shared__ int lds[256];
    int t = threadIdx.x;
    int i = blockIdx.x * 256 + t;
    int v = (i < N) ? cnt[i] : 0;
    lds[t] = v;
    __syncthreads();
    for (int off = 1; off < 256; off <<= 1) {
        int u = (t >= off) ? lds[t - off] : 0;
        __syncthreads();
        lds[t] += u;
        __syncthreads();
    }
    if (i < N) rowptr[i] = part[blockIdx.x] + lds[t] - v;
}

// ---------------- dinv = rsqrt(cnt + 1) ----------------
__global__ __launch_bounds__(256) void k_dinv(const int* __restrict__ cnt, float* __restrict__ dinv, int N) {
    int i = blockIdx.x * 256 + threadIdx.x;
    if (i < N) dinv[i] = rsqrtf((float)cnt[i] + 1.0f);
}

// ---------------- fill adjacency ----------------
__global__ __launch_bounds__(256) void k_fill(const int* __restrict__ src, const int* __restrict__ dst,
                                              const float* __restrict__ dinv, const int* __restrict__ rowptr,
                                              int* __restrict__ cursor, int2* __restrict__ adj, int E) {
    int e = blockIdx.x * 256 + threadIdx.x;
    if (e >= E) return;
    int s = src[e], d = dst[e];
    int pos = atomicAdd(&cursor[d], 1);
    float w = dinv[s] * dinv[d];
    adj[rowptr[d] + pos] = make_int2(s, __float_as_int(w));
}

// ---------------- W[k][c] fp32 -> WT[c][k] bf16 ----------------
__global__ __launch_bounds__(256) void k_prepW(const float* __restrict__ W, unsigned short* __restrict__ WT) {
    int idx = blockIdx.x * 256 + threadIdx.x;   // 16384
    int k = idx >> 7, c = idx & 127;
    WT[c * DD + k] = f2b(W[idx]);
}

// ---------------- MFMA GEMM: H_bf16[N,128] = X[N,128] @ W ----------------
// block: 64 rows, 256 threads (4 waves); wave w -> rows [w*16, w*16+16), all 128 cols.
// LDS swizzle: byte ^= ((row&7)<<4) on 16B chunks (kills stride-256B bank conflicts).
__global__ __launch_bounds__(256) void k_gemm_mfma(const float* __restrict__ X,
                                                   const unsigned short* __restrict__ WT,
                                                   unsigned short* __restrict__ H, int N) {
    __shared__ __align__(16) unsigned short sB[DD * DD];   // WT swizzled, 32 KB
    __shared__ __align__(16) unsigned short sA[64 * DD];   // X tile swizzled, 16 KB
    int tid = threadIdx.x;
    long row0 = (long)blockIdx.x * 64;

    // stage WT -> sB (2048 chunks of 16B, 8 per thread), coalesced global read
#pragma unroll
    for (int i = 0; i < 8; ++i) {
        int q = tid + 256 * i;
        int c = q >> 4, j = q & 15;
        short8 v = *(const short8*)(WT + q * 8);
        int byte = c * 256 + ((j * 16) ^ ((c & 7) << 4));
        *(short8*)((char*)sB + byte) = v;
    }
    // stage X -> sA (1024 chunks, 4 per thread): fp32 -> bf16
#pragma unroll
    for (int i = 0; i < 4; ++i) {
        int q = tid + 256 * i;
        int r = q >> 4, j = q & 15;
        float4 a0 = make_float4(0.f, 0.f, 0.f, 0.f), a1 = a0;
        if (row0 + r < N) {
            const float4* p = (const float4*)(X + (row0 + r) * DD + j * 8);
            a0 = p[0];
            a1 = p[1];
        }
        short8 v;
        v[0] = (short)f2b(a0.x); v[1] = (short)f2b(a0.y);
        v[2] = (short)f2b(a0.z); v[3] = (short)f2b(a0.w);
        v[4] = (short)f2b(a1.x); v[5] = (short)f2b(a1.y);
        v[6] = (short)f2b(a1.z); v[7] = (short)f2b(a1.w);
        int byte = r * 256 + ((j * 16) ^ ((r & 7) << 4));
        *(short8*)((char*)sA + byte) = v;
    }
    __syncthreads();

    int w = tid >> 6, l = tid & 63;
    int lr = l & 15, kg = l >> 4;
    f32x4 acc[8] = {};

#pragma unroll
    for (int step = 0; step < 4; ++step) {
        int ar = w * 16 + lr;
        int abyte = ar * 256 + ((step * 64 + kg * 16) ^ ((ar & 7) << 4));
        short8 af = *(const short8*)((const char*)sA + abyte);
#pragma unroll
        for (int ct = 0; ct < 8; ++ct) {
            int c = ct * 16 + lr;
            int bbyte = c * 256 + ((step * 64 + kg * 16) ^ ((c & 7) << 4));
            short8 bf = *(const short8*)((const char*)sB + bbyte);
            acc[ct] = __builtin_amdgcn_mfma_f32_16x16x32_bf16(af, bf, acc[ct], 0, 0, 0);
        }
    }

    // C/D layout: col = l&15, row = (l>>4)*4 + reg
#pragma unroll
    for (int ct = 0; ct < 8; ++ct) {
#pragma unroll
        for (int reg = 0; reg < 4; ++reg) {
            long r = row0 + w * 16 + kg * 4 + reg;
            if (r < N) H[r * DD + ct * 16 + lr] = f2b(acc[ct][reg]);
        }
    }
}

// ------- fused: aggregate (self+bias+neighbors, h in bf16) -> LN -> residual -> SiLU -------
__global__ __launch_bounds__(256) void k_agg(const unsigned short* __restrict__ h, const float* __restrict__ xin,
                                             const int* __restrict__ rowptr, const int2* __restrict__ adj,
                                             const float* __restrict__ dinv, const float* __restrict__ b,
                                             const float* __restrict__ g, const float* __restrict__ be,
                                             float* __restrict__ xout, int N) {
    int row = blockIdx.x * 4 + (threadIdx.x >> 6);
    if (row >= N) return;
    int lane = threadIdx.x & 63;
    const unsigned int* hu = (const unsigned int*)h;   // 2 bf16 per uint

    float dv = dinv[row];
    float dv2 = dv * dv;
    unsigned int us = hu[(size_t)row * 64 + lane];
    float2 bv = ((const float2*)b)[lane];
    float2 acc = make_float2(fmaf(b2f((unsigned short)(us & 0xFFFF)), dv2, bv.x),
                             fmaf(b2f((unsigned short)(us >> 16)), dv2, bv.y));

    int beg = rowptr[row], end = rowptr[row + 1];
    for (int j0 = beg; j0 < end; j0 += 64) {
        int myj = j0 + lane;
        int2 a = make_int2(0, 0);
        if (myj < end) a = adj[myj];
        int cnt = min(64, end - j0);
        for (int k = 0; k < cnt; ++k) {
            int s = __shfl(a.x, k, 64);
            float w = __int_as_float(__shfl(a.y, k, 64));
            unsigned int un = hu[(size_t)s * 64 + lane];
            acc.x = fmaf(w, b2f((unsigned short)(un & 0xFFFF)), acc.x);
            acc.y = fmaf(w, b2f((unsigned short)(un >> 16)), acc.y);
        }
    }

    // LayerNorm over 128
    float ssum = acc.x + acc.y;
#pragma unroll
    for (int o = 32; o > 0; o >>= 1) ssum += __shfl_xor(ssum, o, 64);
    float mu = ssum * (1.0f / 128.0f);
    float dx0 = acc.x - mu, dx1 = acc.y - mu;
    float vs = dx0 * dx0 + dx1 * dx1;
#pragma unroll
    for (int o = 32; o > 0; o >>= 1) vs += __shfl_xor(vs, o, 64);
    float rstd = rsqrtf(vs * (1.0f / 128.0f) + 1e-5f);

    float2 gv = ((const float2*)g)[lane];
    float2 bev = ((const float2*)be)[lane];
    float2 xv = ((const float2*)(xin + (size_t)row * DD))[lane];
    float a0 = fmaf(dx0 * rstd, gv.x, bev.x) + xv.x;
    float a1 = fmaf(dx1 * rstd, gv.y, bev.y) + xv.y;
    a0 = a0 / (1.0f + expf(-a0));
    a1 = a1 / (1.0f + expf(-a1));
    ((float2*)(xout + (size_t)row * DD))[lane] = make_float2(a0, a1);
}

// ------- pool: one block per graph (batch sorted -> contiguous ranges) -------
__global__ __launch_bounds__(256) void k_pool2(const float* __restrict__ x, const int* __restrict__ batch,
                                               float* __restrict__ out, int N) {
    int gi = blockIdx.x;
    int lo = 0, hi = N;
    while (lo < hi) { int m = (lo + hi) >> 1; if (batch[m] < gi) lo = m + 1; else hi = m; }
    int beg = lo;
    lo = beg; hi = N;
    while (lo < hi) { int m = (lo + hi) >> 1; if (batch[m] < gi + 1) lo = m + 1; else hi = m; }
    int end = lo;

    int tid = threadIdx.x;
    int wave = tid >> 6, lane = tid & 63;
    float2 acc = make_float2(0.f, 0.f);
    for (int r = beg + wave; r < end; r += 4) {
        float2 v = ((const float2*)(x + (size_t)r * DD))[lane];
        acc.x += v.x;
        acc.y += v.y;
    }
    __shared__ float part[4][DD];
    ((float2*)part[wave])[lane] = acc;
    __syncthreads();
    if (wave == 0) {
        float sx = 0.f, sy = 0.f;
#pragma unroll
        for (int w = 0; w < 4; ++w) {
            float2 v = ((const float2*)part[w])[lane];
            sx += v.x;
            sy += v.y;
        }
        float inv = 1.0f / fmaxf((float)(end - beg), 1.0f);
        ((float2*)(out + (size_t)gi * DD))[lane] = make_float2(sx * inv, sy * inv);
    }
}

extern "C" void kernel_launch(void* const* d_in, const int* in_sizes, int n_in,
                              void* d_out, int out_size, void* d_ws, size_t ws_size,
                              hipStream_t stream) {
    const float* x = (const float*)d_in[0];
    const int* edge = (const int*)d_in[1];
    const int* batch = (const int*)d_in[2];
    const float* W[3] = {(const float*)d_in[3], (const float*)d_in[7], (const float*)d_in[11]};
    const float* b[3] = {(const float*)d_in[4], (const float*)d_in[8], (const float*)d_in[12]};
    const float* g[3] = {(const float*)d_in[5], (const float*)d_in[9], (const float*)d_in[13]};
    const float* be[3] = {(const float*)d_in[6], (const float*)d_in[10], (const float*)d_in[14]};

    int N = in_sizes[0] / DD;
    int E = in_sizes[1] / 2;
    int G = out_size / DD;
    const int* srcI = edge;
    const int* dstI = edge + E;

    int nblk = (N + 255) / 256;

    char* ws = (char*)d_ws;
    size_t ND = (size_t)N * DD;
    float* bufX = (float*)ws;                         ws += ND * 4;
    unsigned short* bufH = (unsigned short*)ws;       ws += ND * 2;
    unsigned short* wt[3];
    for (int l = 0; l < 3; ++l) { wt[l] = (unsigned short*)ws; ws += (size_t)DD * DD * 2; }
    float* dinv = (float*)ws;                         ws += (size_t)N * 4;
    int* cnt = (int*)ws;                              ws += (size_t)N * 4;
    int* cursor = (int*)ws;                           ws += (size_t)N * 4;
    int* rowptr = (int*)ws;                           ws += (size_t)(N + 1) * 4;
    int* part = (int*)ws;                             ws += (size_t)nblk * 4;
    ws = (char*)(((uintptr_t)ws + 15) & ~(uintptr_t)15);
    int2* adj = (int2*)ws;

    hipMemsetAsync(cnt, 0, (size_t)N * 2 * 4, stream);

    k_count<<<(E + 255) / 256, 256, 0, stream>>>(dstI, cnt, E);
    k_scan1<<<nblk, 256, 0, stream>>>(cnt, part, N);
    k_scan2<<<1, 1024, 0, stream>>>(part, rowptr, nblk, N);
    k_scan3<<<nblk, 256, 0, stream>>>(cnt, part, rowptr, N);
    k_dinv<<<(N + 255) / 256, 256, 0, stream>>>(cnt, dinv, N);
    k_fill<<<(E + 255) / 256, 256, 0, stream>>>(srcI, dstI, dinv, rowptr, cursor, adj, E);
    for (int l = 0; l < 3; ++l)
        k_prepW<<<64, 256, 0, stream>>>(W[l], wt[l]);

    const float* xin = x;
    for (int l = 0; l < 3; ++l) {
        k_gemm_mfma<<<(N + 63) / 64, 256, 0, stream>>>(xin, wt[l], bufH, N);
        k_agg<<<(N + 3) / 4, 256, 0, stream>>>(bufH, xin, rowptr, adj, dinv, b[l], g[l], be[l], bufX, N);
        xin = bufX;
    }

    k_pool2<<<G, 256, 0, stream>>>(bufX, batch, (float*)d_out, N);
}

// Round 10
// 248.273 us; speedup vs baseline: 14.5126x; 1.2110x over previous
//
#include <hip/hip_runtime.h>
#include <math.h>

#define DD 128

typedef __attribute__((ext_vector_type(8))) short short8;
typedef __attribute__((ext_vector_type(4))) float f32x4;

__device__ __forceinline__ unsigned short f2b(float f) {
    unsigned int x = __float_as_uint(f);
    return (unsigned short)((x + 0x7FFFu + ((x >> 16) & 1u)) >> 16);   // RNE bf16
}
__device__ __forceinline__ float b2f(unsigned short u) {
    return __uint_as_float(((unsigned int)u) << 16);
}

// ---------------- degree histogram (int) ----------------
__global__ __launch_bounds__(256) void k_count(const int* __restrict__ dst, int* __restrict__ cnt, int E) {
    int e = blockIdx.x * 256 + threadIdx.x;
    if (e < E) atomicAdd(&cnt[dst[e]], 1);
}

// ---------------- hierarchical scan ----------------
__global__ __launch_bounds__(256) void k_scan1(const int* __restrict__ cnt, int* __restrict__ part, int N) {
    __shared__ int lds[256];
    int t = threadIdx.x;
    int i = blockIdx.x * 256 + t;
    lds[t] = (i < N) ? cnt[i] : 0;
    __syncthreads();
#pragma unroll
    for (int off = 128; off > 0; off >>= 1) {
        if (t < off) lds[t] += lds[t + off];
        __syncthreads();
    }
    if (t == 0) part[blockIdx.x] = lds[0];
}

__global__ __launch_bounds__(1024) void k_scan2(int* __restrict__ part, int* __restrict__ rowptr,
                                                int nblk, int N) {
    __shared__ int lds[1024];
    int t = threadIdx.x;
    int v = (t < nblk) ? part[t] : 0;
    lds[t] = v;
    __syncthreads();
    for (int off = 1; off < 1024; off <<= 1) {
        int u = (t >= off) ? lds[t - off] : 0;
        __syncthreads();
        lds[t] += u;
        __syncthreads();
    }
    if (t < nblk) part[t] = lds[t] - v;
    if (t == 1023) rowptr[N] = lds[1023];
}

__global__ __launch_bounds__(256) void k_scan3(const int* __restrict__ cnt, const int* __restrict__ part,
                                               int* __restrict__ rowptr, int N) {
    __shared__ int lds[256];
    int t = threadIdx.x;
    int i = blockIdx.x * 256 + t;
    int v = (i < N) ? cnt[i] : 0;
    lds[t] = v;
    __syncthreads();
    for (int off = 1; off < 256; off <<= 1) {
        int u = (t >= off) ? lds[t - off] : 0;
        __syncthreads();
        lds[t] += u;
        __syncthreads();
    }
    if (i < N) rowptr[i] = part[blockIdx.x] + lds[t] - v;
}

// ---------------- dinv = rsqrt(cnt + 1) ----------------
__global__ __launch_bounds__(256) void k_dinv(const int* __restrict__ cnt, float* __restrict__ dinv, int N) {
    int i = blockIdx.x * 256 + threadIdx.x;
    if (i < N) dinv[i] = rsqrtf((float)cnt[i] + 1.0f);
}

// ---------------- fill adjacency ----------------
__global__ __launch_bounds__(256) void k_fill(const int* __restrict__ src, const int* __restrict__ dst,
                                              const float* __restrict__ dinv, const int* __restrict__ rowptr,
                                              int* __restrict__ cursor, int2* __restrict__ adj, int E) {
    int e = blockIdx.x * 256 + threadIdx.x;
    if (e >= E) return;
    int s = src[e], d = dst[e];
    int pos = atomicAdd(&cursor[d], 1);
    float w = dinv[s] * dinv[d];
    adj[rowptr[d] + pos] = make_int2(s, __float_as_int(w));
}

// ---------------- W[k][c] fp32 -> WT[c][k] bf16 ----------------
__global__ __launch_bounds__(256) void k_prepW(const float* __restrict__ W, unsigned short* __restrict__ WT) {
    int idx = blockIdx.x * 256 + threadIdx.x;   // 16384
    int k = idx >> 7, c = idx & 127;
    WT[c * DD + k] = f2b(W[idx]);
}

// ---------------- MFMA GEMM: H_bf16[N,128] = X[N,128] @ W ----------------
__global__ __launch_bounds__(256) void k_gemm_mfma(const float* __restrict__ X,
                                                   const unsigned short* __restrict__ WT,
                                                   unsigned short* __restrict__ H, int N) {
    __shared__ __align__(16) unsigned short sB[DD * DD];   // WT swizzled, 32 KB
    __shared__ __align__(16) unsigned short sA[64 * DD];   // X tile swizzled, 16 KB
    int tid = threadIdx.x;
    long row0 = (long)blockIdx.x * 64;

#pragma unroll
    for (int i = 0; i < 8; ++i) {
        int q = tid + 256 * i;
        int c = q >> 4, j = q & 15;
        short8 v = *(const short8*)(WT + q * 8);
        int byte = c * 256 + ((j * 16) ^ ((c & 7) << 4));
        *(short8*)((char*)sB + byte) = v;
    }
#pragma unroll
    for (int i = 0; i < 4; ++i) {
        int q = tid + 256 * i;
        int r = q >> 4, j = q & 15;
        float4 a0 = make_float4(0.f, 0.f, 0.f, 0.f), a1 = a0;
        if (row0 + r < N) {
            const float4* p = (const float4*)(X + (row0 + r) * DD + j * 8);
            a0 = p[0];
            a1 = p[1];
        }
        short8 v;
        v[0] = (short)f2b(a0.x); v[1] = (short)f2b(a0.y);
        v[2] = (short)f2b(a0.z); v[3] = (short)f2b(a0.w);
        v[4] = (short)f2b(a1.x); v[5] = (short)f2b(a1.y);
        v[6] = (short)f2b(a1.z); v[7] = (short)f2b(a1.w);
        int byte = r * 256 + ((j * 16) ^ ((r & 7) << 4));
        *(short8*)((char*)sA + byte) = v;
    }
    __syncthreads();

    int w = tid >> 6, l = tid & 63;
    int lr = l & 15, kg = l >> 4;
    f32x4 acc[8] = {};

#pragma unroll
    for (int step = 0; step < 4; ++step) {
        int ar = w * 16 + lr;
        int abyte = ar * 256 + ((step * 64 + kg * 16) ^ ((ar & 7) << 4));
        short8 af = *(const short8*)((const char*)sA + abyte);
#pragma unroll
        for (int ct = 0; ct < 8; ++ct) {
            int c = ct * 16 + lr;
            int bbyte = c * 256 + ((step * 64 + kg * 16) ^ ((c & 7) << 4));
            short8 bf = *(const short8*)((const char*)sB + bbyte);
            acc[ct] = __builtin_amdgcn_mfma_f32_16x16x32_bf16(af, bf, acc[ct], 0, 0, 0);
        }
    }

    // C/D layout: col = l&15, row = (l>>4)*4 + reg
#pragma unroll
    for (int ct = 0; ct < 8; ++ct) {
#pragma unroll
        for (int reg = 0; reg < 4; ++reg) {
            long r = row0 + w * 16 + kg * 4 + reg;
            if (r < N) H[r * DD + ct * 16 + lr] = f2b(acc[ct][reg]);
        }
    }
}

// ------- fused: aggregate (self+bias+neighbors, h in bf16) -> LN -> residual -> SiLU -------
// Inner loop: lanes with myj>=end hold a=(0,0) => shfl for k>=cnt gives s=0,w=0
// (harmless gather of h[0] * 0). So round cnt up to 8 and unroll -> 8 independent
// gathers in flight per wave instead of 1 (the round-9 profile showed a serial
// dependent-load chain at L3 latency: 51us, VALUBusy 37%).
__global__ __launch_bounds__(256) void k_agg(const unsigned short* __restrict__ h, const float* __restrict__ xin,
                                             const int* __restrict__ rowptr, const int2* __restrict__ adj,
                                             const float* __restrict__ dinv, const float* __restrict__ b,
                                             const float* __restrict__ g, const float* __restrict__ be,
                                             float* __restrict__ xout, int N) {
    int row = blockIdx.x * 4 + (threadIdx.x >> 6);
    if (row >= N) return;
    int lane = threadIdx.x & 63;
    const unsigned int* hu = (const unsigned int*)h;   // 2 bf16 per uint

    float dv = dinv[row];
    float dv2 = dv * dv;
    unsigned int us = hu[(size_t)row * 64 + lane];
    float2 bv = ((const float2*)b)[lane];
    float2 acc = make_float2(fmaf(b2f((unsigned short)(us & 0xFFFF)), dv2, bv.x),
                             fmaf(b2f((unsigned short)(us >> 16)), dv2, bv.y));

    int beg = rowptr[row], end = rowptr[row + 1];
    for (int j0 = beg; j0 < end; j0 += 64) {
        int myj = j0 + lane;
        int2 a = make_int2(0, 0);
        if (myj < end) a = adj[myj];
        int cnt = min(64, end - j0);
        int cntR = (cnt + 7) & ~7;
        for (int k0 = 0; k0 < cntR; k0 += 8) {
            unsigned int un[8];
            float wt[8];
#pragma unroll
            for (int u = 0; u < 8; ++u) {
                int s = __shfl(a.x, k0 + u, 64);
                wt[u] = __int_as_float(__shfl(a.y, k0 + u, 64));
                un[u] = hu[(size_t)s * 64 + lane];
            }
#pragma unroll
            for (int u = 0; u < 8; ++u) {
                acc.x = fmaf(wt[u], b2f((unsigned short)(un[u] & 0xFFFF)), acc.x);
                acc.y = fmaf(wt[u], b2f((unsigned short)(un[u] >> 16)), acc.y);
            }
        }
    }

    // LayerNorm over 128
    float ssum = acc.x + acc.y;
#pragma unroll
    for (int o = 32; o > 0; o >>= 1) ssum += __shfl_xor(ssum, o, 64);
    float mu = ssum * (1.0f / 128.0f);
    float dx0 = acc.x - mu, dx1 = acc.y - mu;
    float vs = dx0 * dx0 + dx1 * dx1;
#pragma unroll
    for (int o = 32; o > 0; o >>= 1) vs += __shfl_xor(vs, o, 64);
    float rstd = rsqrtf(vs * (1.0f / 128.0f) + 1e-5f);

    float2 gv = ((const float2*)g)[lane];
    float2 bev = ((const float2*)be)[lane];
    float2 xv = ((const float2*)(xin + (size_t)row * DD))[lane];
    float a0 = fmaf(dx0 * rstd, gv.x, bev.x) + xv.x;
    float a1 = fmaf(dx1 * rstd, gv.y, bev.y) + xv.y;
    a0 = a0 / (1.0f + expf(-a0));
    a1 = a1 / (1.0f + expf(-a1));
    ((float2*)(xout + (size_t)row * DD))[lane] = make_float2(a0, a1);
}

// ------- pool: one block per graph (batch sorted -> contiguous ranges) -------
__global__ __launch_bounds__(256) void k_pool2(const float* __restrict__ x, const int* __restrict__ batch,
                                               float* __restrict__ out, int N) {
    int gi = blockIdx.x;
    int lo = 0, hi = N;
    while (lo < hi) { int m = (lo + hi) >> 1; if (batch[m] < gi) lo = m + 1; else hi = m; }
    int beg = lo;
    lo = beg; hi = N;
    while (lo < hi) { int m = (lo + hi) >> 1; if (batch[m] < gi + 1) lo = m + 1; else hi = m; }
    int end = lo;

    int tid = threadIdx.x;
    int wave = tid >> 6, lane = tid & 63;
    float2 acc = make_float2(0.f, 0.f);
    for (int r = beg + wave; r < end; r += 4) {
        float2 v = ((const float2*)(x + (size_t)r * DD))[lane];
        acc.x += v.x;
        acc.y += v.y;
    }
    __shared__ float part[4][DD];
    ((float2*)part[wave])[lane] = acc;
    __syncthreads();
    if (wave == 0) {
        float sx = 0.f, sy = 0.f;
#pragma unroll
        for (int w = 0; w < 4; ++w) {
            float2 v = ((const float2*)part[w])[lane];
            sx += v.x;
            sy += v.y;
        }
        float inv = 1.0f / fmaxf((float)(end - beg), 1.0f);
        ((float2*)(out + (size_t)gi * DD))[lane] = make_float2(sx * inv, sy * inv);
    }
}

extern "C" void kernel_launch(void* const* d_in, const int* in_sizes, int n_in,
                              void* d_out, int out_size, void* d_ws, size_t ws_size,
                              hipStream_t stream) {
    const float* x = (const float*)d_in[0];
    const int* edge = (const int*)d_in[1];
    const int* batch = (const int*)d_in[2];
    const float* W[3] = {(const float*)d_in[3], (const float*)d_in[7], (const float*)d_in[11]};
    const float* b[3] = {(const float*)d_in[4], (const float*)d_in[8], (const float*)d_in[12]};
    const float* g[3] = {(const float*)d_in[5], (const float*)d_in[9], (const float*)d_in[13]};
    const float* be[3] = {(const float*)d_in[6], (const float*)d_in[10], (const float*)d_in[14]};

    int N = in_sizes[0] / DD;
    int E = in_sizes[1] / 2;
    int G = out_size / DD;
    const int* srcI = edge;
    const int* dstI = edge + E;

    int nblk = (N + 255) / 256;

    char* ws = (char*)d_ws;
    size_t ND = (size_t)N * DD;
    float* bufX = (float*)ws;                         ws += ND * 4;
    unsigned short* bufH = (unsigned short*)ws;       ws += ND * 2;
    unsigned short* wt[3];
    for (int l = 0; l < 3; ++l) { wt[l] = (unsigned short*)ws; ws += (size_t)DD * DD * 2; }
    float* dinv = (float*)ws;                         ws += (size_t)N * 4;
    int* cnt = (int*)ws;                              ws += (size_t)N * 4;
    int* cursor = (int*)ws;                           ws += (size_t)N * 4;
    int* rowptr = (int*)ws;                           ws += (size_t)(N + 1) * 4;
    int* part = (int*)ws;                             ws += (size_t)nblk * 4;
    ws = (char*)(((uintptr_t)ws + 15) & ~(uintptr_t)15);
    int2* adj = (int2*)ws;

    hipMemsetAsync(cnt, 0, (size_t)N * 2 * 4, stream);

    k_count<<<(E + 255) / 256, 256, 0, stream>>>(dstI, cnt, E);
    k_scan1<<<nblk, 256, 0, stream>>>(cnt, part, N);
    k_scan2<<<1, 1024, 0, stream>>>(part, rowptr, nblk, N);
    k_scan3<<<nblk, 256, 0, stream>>>(cnt, part, rowptr, N);
    k_dinv<<<(N + 255) / 256, 256, 0, stream>>>(cnt, dinv, N);
    k_fill<<<(E + 255) / 256, 256, 0, stream>>>(srcI, dstI, dinv, rowptr, cursor, adj, E);
    for (int l = 0; l < 3; ++l)
        k_prepW<<<64, 256, 0, stream>>>(W[l], wt[l]);

    const float* xin = x;
    for (int l = 0; l < 3; ++l) {
        k_gemm_mfma<<<(N + 63) / 64, 256, 0, stream>>>(xin, wt[l], bufH, N);
        k_agg<<<(N + 3) / 4, 256, 0, stream>>>(bufH, xin, rowptr, adj, dinv, b[l], g[l], be[l], bufX, N);
        xin = bufX;
    }

    k_pool2<<<G, 256, 0, stream>>>(bufX, batch, (float*)d_out, N);
}

// Round 11
// 240.750 us; speedup vs baseline: 14.9661x; 1.0312x over previous
//
#include <hip/hip_runtime.h>
#include <math.h>

#define DD 128

typedef __attribute__((ext_vector_type(8))) short short8;
typedef __attribute__((ext_vector_type(4))) float f32x4;

__device__ __forceinline__ unsigned short f2b(float f) {
    unsigned int x = __float_as_uint(f);
    return (unsigned short)((x + 0x7FFFu + ((x >> 16) & 1u)) >> 16);   // RNE bf16
}
__device__ __forceinline__ float b2f(unsigned short u) {
    return __uint_as_float(((unsigned int)u) << 16);
}

// ---------------- degree histogram (int) ----------------
__global__ __launch_bounds__(256) void k_count(const int* __restrict__ dst, int* __restrict__ cnt, int E) {
    int e = blockIdx.x * 256 + threadIdx.x;
    if (e < E) atomicAdd(&cnt[dst[e]], 1);
}

// ---------------- hierarchical scan ----------------
__global__ __launch_bounds__(256) void k_scan1(const int* __restrict__ cnt, int* __restrict__ part, int N) {
    __shared__ int lds[256];
    int t = threadIdx.x;
    int i = blockIdx.x * 256 + t;
    lds[t] = (i < N) ? cnt[i] : 0;
    __syncthreads();
#pragma unroll
    for (int off = 128; off > 0; off >>= 1) {
        if (t < off) lds[t] += lds[t + off];
        __syncthreads();
    }
    if (t == 0) part[blockIdx.x] = lds[0];
}

__global__ __launch_bounds__(1024) void k_scan2(int* __restrict__ part, int* __restrict__ rowptr,
                                                int nblk, int N) {
    __shared__ int lds[1024];
    int t = threadIdx.x;
    int v = (t < nblk) ? part[t] : 0;
    lds[t] = v;
    __syncthreads();
    for (int off = 1; off < 1024; off <<= 1) {
        int u = (t >= off) ? lds[t - off] : 0;
        __syncthreads();
        lds[t] += u;
        __syncthreads();
    }
    if (t < nblk) part[t] = lds[t] - v;
    if (t == 1023) rowptr[N] = lds[1023];
}

// scan3 + dinv fused (cnt already in registers)
__global__ __launch_bounds__(256) void k_scan3(const int* __restrict__ cnt, const int* __restrict__ part,
                                               int* __restrict__ rowptr, float* __restrict__ dinv, int N) {
    __shared__ int lds[256];
    int t = threadIdx.x;
    int i = blockIdx.x * 256 + t;
    int v = (i < N) ? cnt[i] : 0;
    lds[t] = v;
    __syncthreads();
    for (int off = 1; off < 256; off <<= 1) {
        int u = (t >= off) ? lds[t - off] : 0;
        __syncthreads();
        lds[t] += u;
        __syncthreads();
    }
    if (i < N) {
        rowptr[i] = part[blockIdx.x] + lds[t] - v;
        dinv[i] = rsqrtf((float)v + 1.0f);
    }
}

// ---------------- fill adjacency ----------------
__global__ __launch_bounds__(256) void k_fill(const int* __restrict__ src, const int* __restrict__ dst,
                                              const float* __restrict__ dinv, const int* __restrict__ rowptr,
                                              int* __restrict__ cursor, int2* __restrict__ adj, int E) {
    int e = blockIdx.x * 256 + threadIdx.x;
    if (e >= E) return;
    int s = src[e], d = dst[e];
    int pos = atomicAdd(&cursor[d], 1);
    float w = dinv[s] * dinv[d];
    adj[rowptr[d] + pos] = make_int2(s, __float_as_int(w));
}

// ---------------- all 3 weights: W[k][c] fp32 -> WT[c][k] bf16, one launch ----------------
__global__ __launch_bounds__(256) void k_prepW3(const float* __restrict__ W0, const float* __restrict__ W1,
                                                const float* __restrict__ W2, unsigned short* __restrict__ T0,
                                                unsigned short* __restrict__ T1, unsigned short* __restrict__ T2) {
    int l = blockIdx.x >> 6;
    const float* W = (l == 0) ? W0 : (l == 1) ? W1 : W2;
    unsigned short* WT = (l == 0) ? T0 : (l == 1) ? T1 : T2;
    int idx = (blockIdx.x & 63) * 256 + threadIdx.x;   // 16384
    int k = idx >> 7, c = idx & 127;
    WT[c * DD + k] = f2b(W[idx]);
}

// ---------------- MFMA GEMM: H_bf16[N,128] = X[N,128] @ W ----------------
// IN_BF16=0: X is fp32 (first layer); IN_BF16=1: X is bf16.
template <int IN_BF16>
__global__ __launch_bounds__(256) void k_gemm_mfma(const void* __restrict__ Xv,
                                                   const unsigned short* __restrict__ WT,
                                                   unsigned short* __restrict__ H, int N) {
    __shared__ __align__(16) unsigned short sB[DD * DD];   // WT swizzled, 32 KB
    __shared__ __align__(16) unsigned short sA[64 * DD];   // X tile swizzled, 16 KB
    int tid = threadIdx.x;
    long row0 = (long)blockIdx.x * 64;

#pragma unroll
    for (int i = 0; i < 8; ++i) {
        int q = tid + 256 * i;
        int c = q >> 4, j = q & 15;
        short8 v = *(const short8*)(WT + q * 8);
        int byte = c * 256 + ((j * 16) ^ ((c & 7) << 4));
        *(short8*)((char*)sB + byte) = v;
    }
#pragma unroll
    for (int i = 0; i < 4; ++i) {
        int q = tid + 256 * i;
        int r = q >> 4, j = q & 15;
        short8 v;
        if (IN_BF16) {
#pragma unroll
            for (int z = 0; z < 8; ++z) v[z] = 0;
            if (row0 + r < N) v = *(const short8*)((const unsigned short*)Xv + (row0 + r) * DD + j * 8);
        } else {
            float4 a0 = make_float4(0.f, 0.f, 0.f, 0.f), a1 = a0;
            if (row0 + r < N) {
                const float4* p = (const float4*)((const float*)Xv + (row0 + r) * DD + j * 8);
                a0 = p[0];
                a1 = p[1];
            }
            v[0] = (short)f2b(a0.x); v[1] = (short)f2b(a0.y);
            v[2] = (short)f2b(a0.z); v[3] = (short)f2b(a0.w);
            v[4] = (short)f2b(a1.x); v[5] = (short)f2b(a1.y);
            v[6] = (short)f2b(a1.z); v[7] = (short)f2b(a1.w);
        }
        int byte = r * 256 + ((j * 16) ^ ((r & 7) << 4));
        *(short8*)((char*)sA + byte) = v;
    }
    __syncthreads();

    int w = tid >> 6, l = tid & 63;
    int lr = l & 15, kg = l >> 4;
    f32x4 acc[8] = {};

#pragma unroll
    for (int step = 0; step < 4; ++step) {
        int ar = w * 16 + lr;
        int abyte = ar * 256 + ((step * 64 + kg * 16) ^ ((ar & 7) << 4));
        short8 af = *(const short8*)((const char*)sA + abyte);
#pragma unroll
        for (int ct = 0; ct < 8; ++ct) {
            int c = ct * 16 + lr;
            int bbyte = c * 256 + ((step * 64 + kg * 16) ^ ((c & 7) << 4));
            short8 bf = *(const short8*)((const char*)sB + bbyte);
            acc[ct] = __builtin_amdgcn_mfma_f32_16x16x32_bf16(af, bf, acc[ct], 0, 0, 0);
        }
    }

    // C/D layout: col = l&15, row = (l>>4)*4 + reg
#pragma unroll
    for (int ct = 0; ct < 8; ++ct) {
#pragma unroll
        for (int reg = 0; reg < 4; ++reg) {
            long r = row0 + w * 16 + kg * 4 + reg;
            if (r < N) H[r * DD + ct * 16 + lr] = f2b(acc[ct][reg]);
        }
    }
}

// ------- fused: aggregate (self+bias+neighbors, h bf16) -> LN -> residual -> SiLU -> x_out bf16 -------
// Inner loop: lanes past end hold a=(0,0) => shfl gives s=0,w=0 (harmless h[0]*0),
// so round cnt to 8 and unroll -> 8 gathers in flight (latency hiding; round-10 win).
template <int IN_BF16>
__global__ __launch_bounds__(256) void k_agg(const unsigned short* __restrict__ h, const void* __restrict__ xin,
                                             const int* __restrict__ rowptr, const int2* __restrict__ adj,
                                             const float* __restrict__ dinv, const float* __restrict__ b,
                                             const float* __restrict__ g, const float* __restrict__ be,
                                             unsigned int* __restrict__ xout, int N) {
    int row = blockIdx.x * 4 + (threadIdx.x >> 6);
    if (row >= N) return;
    int lane = threadIdx.x & 63;
    const unsigned int* hu = (const unsigned int*)h;   // 2 bf16 per uint

    float dv = dinv[row];
    float dv2 = dv * dv;
    unsigned int us = hu[(size_t)row * 64 + lane];
    float2 bv = ((const float2*)b)[lane];
    float2 acc = make_float2(fmaf(b2f((unsigned short)(us & 0xFFFF)), dv2, bv.x),
                             fmaf(b2f((unsigned short)(us >> 16)), dv2, bv.y));

    int beg = rowptr[row], end = rowptr[row + 1];
    for (int j0 = beg; j0 < end; j0 += 64) {
        int myj = j0 + lane;
        int2 a = make_int2(0, 0);
        if (myj < end) a = adj[myj];
        int cnt = min(64, end - j0);
        int cntR = (cnt + 7) & ~7;
        for (int k0 = 0; k0 < cntR; k0 += 8) {
            unsigned int un[8];
            float wt[8];
#pragma unroll
            for (int u = 0; u < 8; ++u) {
                int s = __shfl(a.x, k0 + u, 64);
                wt[u] = __int_as_float(__shfl(a.y, k0 + u, 64));
                un[u] = hu[(size_t)s * 64 + lane];
            }
#pragma unroll
            for (int u = 0; u < 8; ++u) {
                acc.x = fmaf(wt[u], b2f((unsigned short)(un[u] & 0xFFFF)), acc.x);
                acc.y = fmaf(wt[u], b2f((unsigned short)(un[u] >> 16)), acc.y);
            }
        }
    }

    // LayerNorm over 128
    float ssum = acc.x + acc.y;
#pragma unroll
    for (int o = 32; o > 0; o >>= 1) ssum += __shfl_xor(ssum, o, 64);
    float mu = ssum * (1.0f / 128.0f);
    float dx0 = acc.x - mu, dx1 = acc.y - mu;
    float vs = dx0 * dx0 + dx1 * dx1;
#pragma unroll
    for (int o = 32; o > 0; o >>= 1) vs += __shfl_xor(vs, o, 64);
    float rstd = rsqrtf(vs * (1.0f / 128.0f) + 1e-5f);

    float2 gv = ((const float2*)g)[lane];
    float2 bev = ((const float2*)be)[lane];
    float2 xv;
    if (IN_BF16) {
        unsigned int xu = ((const unsigned int*)xin)[(size_t)row * 64 + lane];
        xv = make_float2(b2f((unsigned short)(xu & 0xFFFF)), b2f((unsigned short)(xu >> 16)));
    } else {
        xv = ((const float2*)xin)[(size_t)row * 64 + lane];
    }
    float a0 = fmaf(dx0 * rstd, gv.x, bev.x) + xv.x;
    float a1 = fmaf(dx1 * rstd, gv.y, bev.y) + xv.y;
    a0 = a0 / (1.0f + expf(-a0));
    a1 = a1 / (1.0f + expf(-a1));
    xout[(size_t)row * 64 + lane] = ((unsigned int)f2b(a1) << 16) | (unsigned int)f2b(a0);
}

// ------- pool: one block per graph (batch sorted -> contiguous ranges), x in bf16 -------
__global__ __launch_bounds__(256) void k_pool2(const unsigned int* __restrict__ x, const int* __restrict__ batch,
                                               float* __restrict__ out, int N) {
    int gi = blockIdx.x;
    int lo = 0, hi = N;
    while (lo < hi) { int m = (lo + hi) >> 1; if (batch[m] < gi) lo = m + 1; else hi = m; }
    int beg = lo;
    lo = beg; hi = N;
    while (lo < hi) { int m = (lo + hi) >> 1; if (batch[m] < gi + 1) lo = m + 1; else hi = m; }
    int end = lo;

    int tid = threadIdx.x;
    int wave = tid >> 6, lane = tid & 63;
    float2 acc = make_float2(0.f, 0.f);
    for (int r = beg + wave; r < end; r += 4) {
        unsigned int u = x[(size_t)r * 64 + lane];
        acc.x += b2f((unsigned short)(u & 0xFFFF));
        acc.y += b2f((unsigned short)(u >> 16));
    }
    __shared__ float part[4][DD];
    ((float2*)part[wave])[lane] = acc;
    __syncthreads();
    if (wave == 0) {
        float sx = 0.f, sy = 0.f;
#pragma unroll
        for (int w = 0; w < 4; ++w) {
            float2 v = ((const float2*)part[w])[lane];
            sx += v.x;
            sy += v.y;
        }
        float inv = 1.0f / fmaxf((float)(end - beg), 1.0f);
        ((float2*)(out + (size_t)gi * DD))[lane] = make_float2(sx * inv, sy * inv);
    }
}

extern "C" void kernel_launch(void* const* d_in, const int* in_sizes, int n_in,
                              void* d_out, int out_size, void* d_ws, size_t ws_size,
                              hipStream_t stream) {
    const float* x = (const float*)d_in[0];
    const int* edge = (const int*)d_in[1];
    const int* batch = (const int*)d_in[2];
    const float* W[3] = {(const float*)d_in[3], (const float*)d_in[7], (const float*)d_in[11]};
    const float* b[3] = {(const float*)d_in[4], (const float*)d_in[8], (const float*)d_in[12]};
    const float* g[3] = {(const float*)d_in[5], (const float*)d_in[9], (const float*)d_in[13]};
    const float* be[3] = {(const float*)d_in[6], (const float*)d_in[10], (const float*)d_in[14]};

    int N = in_sizes[0] / DD;
    int E = in_sizes[1] / 2;
    int G = out_size / DD;
    const int* srcI = edge;
    const int* dstI = edge + E;

    int nblk = (N + 255) / 256;

    char* ws = (char*)d_ws;
    size_t ND = (size_t)N * DD;
    unsigned int* bufX = (unsigned int*)ws;           ws += ND * 2;   // x state, bf16
    unsigned short* bufH = (unsigned short*)ws;       ws += ND * 2;   // h, bf16
    unsigned short* wt[3];
    for (int l = 0; l < 3; ++l) { wt[l] = (unsigned short*)ws; ws += (size_t)DD * DD * 2; }
    float* dinv = (float*)ws;                         ws += (size_t)N * 4;
    int* cnt = (int*)ws;                              ws += (size_t)N * 4;
    int* cursor = (int*)ws;                           ws += (size_t)N * 4;
    int* rowptr = (int*)ws;                           ws += (size_t)(N + 1) * 4;
    int* part = (int*)ws;                             ws += (size_t)nblk * 4;
    ws = (char*)(((uintptr_t)ws + 15) & ~(uintptr_t)15);
    int2* adj = (int2*)ws;

    hipMemsetAsync(cnt, 0, (size_t)N * 2 * 4, stream);

    k_count<<<(E + 255) / 256, 256, 0, stream>>>(dstI, cnt, E);
    k_scan1<<<nblk, 256, 0, stream>>>(cnt, part, N);
    k_scan2<<<1, 1024, 0, stream>>>(part, rowptr, nblk, N);
    k_scan3<<<nblk, 256, 0, stream>>>(cnt, part, rowptr, dinv, N);
    k_fill<<<(E + 255) / 256, 256, 0, stream>>>(srcI, dstI, dinv, rowptr, cursor, adj, E);
    k_prepW3<<<192, 256, 0, stream>>>(W[0], W[1], W[2], wt[0], wt[1], wt[2]);

    int gblk = (N + 63) / 64, ablk = (N + 3) / 4;
    // layer 0: fp32 input
    k_gemm_mfma<0><<<gblk, 256, 0, stream>>>(x, wt[0], bufH, N);
    k_agg<0><<<ablk, 256, 0, stream>>>(bufH, x, rowptr, adj, dinv, b[0], g[0], be[0], bufX, N);
    // layers 1,2: bf16 state (in-place safe: each thread reads own row before writing)
    for (int l = 1; l < 3; ++l) {
        k_gemm_mfma<1><<<gblk, 256, 0, stream>>>(bufX, wt[l], bufH, N);
        k_agg<1><<<ablk, 256, 0, stream>>>(bufH, bufX, rowptr, adj, dinv, b[l], g[l], be[l], bufX, N);
    }

    k_pool2<<<G, 256, 0, stream>>>(bufX, batch, (float*)d_out, N);
}

// Round 12
// 238.838 us; speedup vs baseline: 15.0859x; 1.0080x over previous
//
#include <hip/hip_runtime.h>
#include <math.h>

#define DD 128

typedef __attribute__((ext_vector_type(8))) short short8;
typedef __attribute__((ext_vector_type(4))) float f32x4;

__device__ __forceinline__ unsigned short f2b(float f) {
    unsigned int x = __float_as_uint(f);
    return (unsigned short)((x + 0x7FFFu + ((x >> 16) & 1u)) >> 16);   // RNE bf16
}
__device__ __forceinline__ float b2f(unsigned short u) {
    return __uint_as_float(((unsigned int)u) << 16);
}

// ---------------- fused setup: blocks [0,192) transpose W->bf16, rest histogram dst ----------------
__global__ __launch_bounds__(256) void k_setup(const int* __restrict__ dst, int* __restrict__ cnt, int E,
                                               const float* __restrict__ W0, const float* __restrict__ W1,
                                               const float* __restrict__ W2, unsigned short* __restrict__ T0,
                                               unsigned short* __restrict__ T1, unsigned short* __restrict__ T2) {
    int bid = blockIdx.x;
    if (bid < 192) {
        int l = bid >> 6;
        const float* W = (l == 0) ? W0 : (l == 1) ? W1 : W2;
        unsigned short* WT = (l == 0) ? T0 : (l == 1) ? T1 : T2;
        int idx = (bid & 63) * 256 + threadIdx.x;   // 16384
        int k = idx >> 7, c = idx & 127;
        WT[c * DD + k] = f2b(W[idx]);
    } else {
        int e = (bid - 192) * 256 + threadIdx.x;
        if (e < E) atomicAdd(&cnt[dst[e]], 1);
    }
}

// ---------------- hierarchical scan ----------------
__global__ __launch_bounds__(256) void k_scan1(const int* __restrict__ cnt, int* __restrict__ part, int N) {
    __shared__ int lds[256];
    int t = threadIdx.x;
    int i = blockIdx.x * 256 + t;
    lds[t] = (i < N) ? cnt[i] : 0;
    __syncthreads();
#pragma unroll
    for (int off = 128; off > 0; off >>= 1) {
        if (t < off) lds[t] += lds[t + off];
        __syncthreads();
    }
    if (t == 0) part[blockIdx.x] = lds[0];
}

__global__ __launch_bounds__(1024) void k_scan2(int* __restrict__ part, int* __restrict__ rowptr,
                                                int nblk, int N) {
    __shared__ int lds[1024];
    int t = threadIdx.x;
    int v = (t < nblk) ? part[t] : 0;
    lds[t] = v;
    __syncthreads();
    for (int off = 1; off < 1024; off <<= 1) {
        int u = (t >= off) ? lds[t - off] : 0;
        __syncthreads();
        lds[t] += u;
        __syncthreads();
    }
    if (t < nblk) part[t] = lds[t] - v;
    if (t == 1023) rowptr[N] = lds[1023];
}

// scan3 + dinv fused
__global__ __launch_bounds__(256) void k_scan3(const int* __restrict__ cnt, const int* __restrict__ part,
                                               int* __restrict__ rowptr, float* __restrict__ dinv, int N) {
    __shared__ int lds[256];
    int t = threadIdx.x;
    int i = blockIdx.x * 256 + t;
    int v = (i < N) ? cnt[i] : 0;
    lds[t] = v;
    __syncthreads();
    for (int off = 1; off < 256; off <<= 1) {
        int u = (t >= off) ? lds[t - off] : 0;
        __syncthreads();
        lds[t] += u;
        __syncthreads();
    }
    if (i < N) {
        rowptr[i] = part[blockIdx.x] + lds[t] - v;
        dinv[i] = rsqrtf((float)v + 1.0f);
    }
}

// ---------------- fill adjacency ----------------
__global__ __launch_bounds__(256) void k_fill(const int* __restrict__ src, const int* __restrict__ dst,
                                              const float* __restrict__ dinv, const int* __restrict__ rowptr,
                                              int* __restrict__ cursor, int2* __restrict__ adj, int E) {
    int e = blockIdx.x * 256 + threadIdx.x;
    if (e >= E) return;
    int s = src[e], d = dst[e];
    int pos = atomicAdd(&cursor[d], 1);
    float w = dinv[s] * dinv[d];
    adj[rowptr[d] + pos] = make_int2(s, __float_as_int(w));
}

// ---------------- MFMA GEMM: H_bf16[N,128] = X[N,128] @ W, 128-row tile ----------------
// 4 waves; wave w -> rows [w*32, w*32+32) as two 16-row strips sharing each B frag.
template <int IN_BF16>
__global__ __launch_bounds__(256) void k_gemm_mfma(const void* __restrict__ Xv,
                                                   const unsigned short* __restrict__ WT,
                                                   unsigned short* __restrict__ H, int N) {
    __shared__ __align__(16) unsigned short sB[DD * DD];    // 32 KB swizzled
    __shared__ __align__(16) unsigned short sA[DD * DD];    // 32 KB swizzled
    int tid = threadIdx.x;
    long row0 = (long)blockIdx.x * 128;

#pragma unroll
    for (int i = 0; i < 8; ++i) {
        int q = tid + 256 * i;
        int c = q >> 4, j = q & 15;
        short8 v = *(const short8*)(WT + q * 8);
        int byte = c * 256 + ((j * 16) ^ ((c & 7) << 4));
        *(short8*)((char*)sB + byte) = v;
    }
#pragma unroll
    for (int i = 0; i < 8; ++i) {
        int q = tid + 256 * i;
        int r = q >> 4, j = q & 15;
        short8 v;
        if (IN_BF16) {
#pragma unroll
            for (int z = 0; z < 8; ++z) v[z] = 0;
            if (row0 + r < N) v = *(const short8*)((const unsigned short*)Xv + (row0 + r) * DD + j * 8);
        } else {
            float4 a0 = make_float4(0.f, 0.f, 0.f, 0.f), a1 = a0;
            if (row0 + r < N) {
                const float4* p = (const float4*)((const float*)Xv + (row0 + r) * DD + j * 8);
                a0 = p[0];
                a1 = p[1];
            }
            v[0] = (short)f2b(a0.x); v[1] = (short)f2b(a0.y);
            v[2] = (short)f2b(a0.z); v[3] = (short)f2b(a0.w);
            v[4] = (short)f2b(a1.x); v[5] = (short)f2b(a1.y);
            v[6] = (short)f2b(a1.z); v[7] = (short)f2b(a1.w);
        }
        int byte = r * 256 + ((j * 16) ^ ((r & 7) << 4));
        *(short8*)((char*)sA + byte) = v;
    }
    __syncthreads();

    int w = tid >> 6, l = tid & 63;
    int lr = l & 15, kg = l >> 4;
    int ar0 = w * 32 + lr, ar1 = w * 32 + 16 + lr;
    f32x4 acc0[8] = {}, acc1[8] = {};

#pragma unroll
    for (int step = 0; step < 4; ++step) {
        int koff = step * 64 + kg * 16;
        short8 a0 = *(const short8*)((const char*)sA + ar0 * 256 + (koff ^ ((ar0 & 7) << 4)));
        short8 a1 = *(const short8*)((const char*)sA + ar1 * 256 + (koff ^ ((ar1 & 7) << 4)));
#pragma unroll
        for (int ct = 0; ct < 8; ++ct) {
            int c = ct * 16 + lr;
            short8 bf = *(const short8*)((const char*)sB + c * 256 + (koff ^ ((c & 7) << 4)));
            acc0[ct] = __builtin_amdgcn_mfma_f32_16x16x32_bf16(a0, bf, acc0[ct], 0, 0, 0);
            acc1[ct] = __builtin_amdgcn_mfma_f32_16x16x32_bf16(a1, bf, acc1[ct], 0, 0, 0);
        }
    }

    // C/D: col = l&15, row = (l>>4)*4 + reg (per 16-row strip)
#pragma unroll
    for (int ct = 0; ct < 8; ++ct) {
#pragma unroll
        for (int reg = 0; reg < 4; ++reg) {
            long r = row0 + w * 32 + kg * 4 + reg;
            if (r < N) H[r * DD + ct * 16 + lr] = f2b(acc0[ct][reg]);
            long r2 = r + 16;
            if (r2 < N) H[r2 * DD + ct * 16 + lr] = f2b(acc1[ct][reg]);
        }
    }
}

// ------- fused: aggregate (h bf16) -> LN -> residual -> SiLU -> x_out bf16 -------
// Padded lanes hold a=(0,0) => shfl gives s=0,w=0 (harmless h[0]*0). Round cnt to 16
// and unroll -> 16 independent gathers in flight (round-10's 8-deep ILP win, deepened).
template <int IN_BF16>
__global__ __launch_bounds__(256) void k_agg(const unsigned short* __restrict__ h, const void* __restrict__ xin,
                                             const int* __restrict__ rowptr, const int2* __restrict__ adj,
                                             const float* __restrict__ dinv, const float* __restrict__ b,
                                             const float* __restrict__ g, const float* __restrict__ be,
                                             unsigned int* __restrict__ xout, int N) {
    int row = blockIdx.x * 4 + (threadIdx.x >> 6);
    if (row >= N) return;
    int lane = threadIdx.x & 63;
    const unsigned int* hu = (const unsigned int*)h;

    float dv = dinv[row];
    float dv2 = dv * dv;
    unsigned int us = hu[(size_t)row * 64 + lane];
    float2 bv = ((const float2*)b)[lane];
    float2 acc = make_float2(fmaf(b2f((unsigned short)(us & 0xFFFF)), dv2, bv.x),
                             fmaf(b2f((unsigned short)(us >> 16)), dv2, bv.y));

    int beg = rowptr[row], end = rowptr[row + 1];
    for (int j0 = beg; j0 < end; j0 += 64) {
        int myj = j0 + lane;
        int2 a = make_int2(0, 0);
        if (myj < end) a = adj[myj];
        int cnt = min(64, end - j0);
        int cntR = (cnt + 15) & ~15;
        for (int k0 = 0; k0 < cntR; k0 += 16) {
            unsigned int un[16];
            float wt[16];
#pragma unroll
            for (int u = 0; u < 16; ++u) {
                int s = __shfl(a.x, k0 + u, 64);
                wt[u] = __int_as_float(__shfl(a.y, k0 + u, 64));
                un[u] = hu[(size_t)s * 64 + lane];
            }
#pragma unroll
            for (int u = 0; u < 16; ++u) {
                acc.x = fmaf(wt[u], b2f((unsigned short)(un[u] & 0xFFFF)), acc.x);
                acc.y = fmaf(wt[u], b2f((unsigned short)(un[u] >> 16)), acc.y);
            }
        }
    }

    // LayerNorm over 128
    float ssum = acc.x + acc.y;
#pragma unroll
    for (int o = 32; o > 0; o >>= 1) ssum += __shfl_xor(ssum, o, 64);
    float mu = ssum * (1.0f / 128.0f);
    float dx0 = acc.x - mu, dx1 = acc.y - mu;
    float vs = dx0 * dx0 + dx1 * dx1;
#pragma unroll
    for (int o = 32; o > 0; o >>= 1) vs += __shfl_xor(vs, o, 64);
    float rstd = rsqrtf(vs * (1.0f / 128.0f) + 1e-5f);

    float2 gv = ((const float2*)g)[lane];
    float2 bev = ((const float2*)be)[lane];
    float2 xv;
    if (IN_BF16) {
        unsigned int xu = ((const unsigned int*)xin)[(size_t)row * 64 + lane];
        xv = make_float2(b2f((unsigned short)(xu & 0xFFFF)), b2f((unsigned short)(xu >> 16)));
    } else {
        xv = ((const float2*)xin)[(size_t)row * 64 + lane];
    }
    float a0 = fmaf(dx0 * rstd, gv.x, bev.x) + xv.x;
    float a1 = fmaf(dx1 * rstd, gv.y, bev.y) + xv.y;
    a0 = a0 / (1.0f + expf(-a0));
    a1 = a1 / (1.0f + expf(-a1));
    xout[(size_t)row * 64 + lane] = ((unsigned int)f2b(a1) << 16) | (unsigned int)f2b(a0);
}

// ------- pool: one block per graph (batch sorted -> contiguous ranges), x bf16 -------
__global__ __launch_bounds__(256) void k_pool2(const unsigned int* __restrict__ x, const int* __restrict__ batch,
                                               float* __restrict__ out, int N) {
    int gi = blockIdx.x;
    int lo = 0, hi = N;
    while (lo < hi) { int m = (lo + hi) >> 1; if (batch[m] < gi) lo = m + 1; else hi = m; }
    int beg = lo;
    lo = beg; hi = N;
    while (lo < hi) { int m = (lo + hi) >> 1; if (batch[m] < gi + 1) lo = m + 1; else hi = m; }
    int end = lo;

    int tid = threadIdx.x;
    int wave = tid >> 6, lane = tid & 63;
    float2 acc = make_float2(0.f, 0.f);
    for (int r = beg + wave; r < end; r += 4) {
        unsigned int u = x[(size_t)r * 64 + lane];
        acc.x += b2f((unsigned short)(u & 0xFFFF));
        acc.y += b2f((unsigned short)(u >> 16));
    }
    __shared__ float part[4][DD];
    ((float2*)part[wave])[lane] = acc;
    __syncthreads();
    if (wave == 0) {
        float sx = 0.f, sy = 0.f;
#pragma unroll
        for (int w = 0; w < 4; ++w) {
            float2 v = ((const float2*)part[w])[lane];
            sx += v.x;
            sy += v.y;
        }
        float inv = 1.0f / fmaxf((float)(end - beg), 1.0f);
        ((float2*)(out + (size_t)gi * DD))[lane] = make_float2(sx * inv, sy * inv);
    }
}

extern "C" void kernel_launch(void* const* d_in, const int* in_sizes, int n_in,
                              void* d_out, int out_size, void* d_ws, size_t ws_size,
                              hipStream_t stream) {
    const float* x = (const float*)d_in[0];
    const int* edge = (const int*)d_in[1];
    const int* batch = (const int*)d_in[2];
    const float* W[3] = {(const float*)d_in[3], (const float*)d_in[7], (const float*)d_in[11]};
    const float* b[3] = {(const float*)d_in[4], (const float*)d_in[8], (const float*)d_in[12]};
    const float* g[3] = {(const float*)d_in[5], (const float*)d_in[9], (const float*)d_in[13]};
    const float* be[3] = {(const float*)d_in[6], (const float*)d_in[10], (const float*)d_in[14]};

    int N = in_sizes[0] / DD;
    int E = in_sizes[1] / 2;
    int G = out_size / DD;
    const int* srcI = edge;
    const int* dstI = edge + E;

    int nblk = (N + 255) / 256;

    char* ws = (char*)d_ws;
    size_t ND = (size_t)N * DD;
    unsigned int* bufX = (unsigned int*)ws;           ws += ND * 2;   // x state, bf16
    unsigned short* bufH = (unsigned short*)ws;       ws += ND * 2;   // h, bf16
    unsigned short* wt[3];
    for (int l = 0; l < 3; ++l) { wt[l] = (unsigned short*)ws; ws += (size_t)DD * DD * 2; }
    float* dinv = (float*)ws;                         ws += (size_t)N * 4;
    int* cnt = (int*)ws;                              ws += (size_t)N * 4;
    int* cursor = (int*)ws;                           ws += (size_t)N * 4;
    int* rowptr = (int*)ws;                           ws += (size_t)(N + 1) * 4;
    int* part = (int*)ws;                             ws += (size_t)nblk * 4;
    ws = (char*)(((uintptr_t)ws + 15) & ~(uintptr_t)15);
    int2* adj = (int2*)ws;

    hipMemsetAsync(cnt, 0, (size_t)N * 2 * 4, stream);

    k_setup<<<192 + (E + 255) / 256, 256, 0, stream>>>(dstI, cnt, E, W[0], W[1], W[2], wt[0], wt[1], wt[2]);
    k_scan1<<<nblk, 256, 0, stream>>>(cnt, part, N);
    k_scan2<<<1, 1024, 0, stream>>>(part, rowptr, nblk, N);
    k_scan3<<<nblk, 256, 0, stream>>>(cnt, part, rowptr, dinv, N);
    k_fill<<<(E + 255) / 256, 256, 0, stream>>>(srcI, dstI, dinv, rowptr, cursor, adj, E);

    int gblk = (N + 127) / 128, ablk = (N + 3) / 4;
    // layer 0: fp32 input
    k_gemm_mfma<0><<<gblk, 256, 0, stream>>>(x, wt[0], bufH, N);
    k_agg<0><<<ablk, 256, 0, stream>>>(bufH, x, rowptr, adj, dinv, b[0], g[0], be[0], bufX, N);
    // layers 1,2: bf16 state (in-place safe: each thread reads own row before writing)
    for (int l = 1; l < 3; ++l) {
        k_gemm_mfma<1><<<gblk, 256, 0, stream>>>(bufX, wt[l], bufH, N);
        k_agg<1><<<ablk, 256, 0, stream>>>(bufH, bufX, rowptr, adj, dinv, b[l], g[l], be[l], bufX, N);
    }

    k_pool2<<<G, 256, 0, stream>>>(bufX, batch, (float*)d_out, N);
}